// Round 7
// baseline (1074.562 us; speedup 1.0000x reference)
//
#include <hip/hip_runtime.h>
#include <hip/hip_bf16.h>
#include <math.h>

#define H 1024
#define B 32
#define T 256
#define L 4
#define O 256
#define TCH 128        // time chunk
#define NCHUNK 2
#define SEGLEN 16
#define NSEG (TCH / SEGLEN)   // 8

typedef _Float16 half8 __attribute__((ext_vector_type(8)));
typedef _Float16 half4 __attribute__((ext_vector_type(4)));
typedef float f32x4 __attribute__((ext_vector_type(4)));

// ws layout (offsets in halves):
#define X_PK_OFF   0            // 8,388,608 halves (T*32 rows, A-frag f16)
#define HB0_OFF    8388608
#define HB1_OFF    16777216
#define WT2_OFF    25165824     // 20,971,520 halves
#define Z16_OFF    46137344     // 20,971,520 halves (chunk: 4096 rows x 5 x 1024 f16)
#define A_OFF      67108864     // 8,388,608 halves = 4096x1024 f32 (prefix prod of f)
#define BC_OFF     75497472     // 8,388,608 halves (local c-scan)
#define BN_OFF     83886080     // 8,388,608 halves (local n-scan)
#define STATS_OFF  92274688     // 98,304 halves = 4096x12 f32
#define CARC_OFF   92372992     // 524,288 halves = 8x32768 f32
#define CARN_OFF   92897280     // 524,288 halves
#define STATE_OFF  93421568     // 524,288 halves = 2*L*B*H f32
#define FCP_OFF    93945856     // 131,072 halves = 65536 f32
#define PSUM_OFF   94076928     // 655,360 halves = 20*4096*4 f32
#define GSUM_OFF   94732288     // 16 halves = 8 f32
// total ~190 MB

__device__ __forceinline__ void gll16(const _Float16* g, _Float16* l) {
  __builtin_amdgcn_global_load_lds(
      (const __attribute__((address_space(1))) void*)g,
      (__attribute__((address_space(3))) void*)l, 16, 0, 0);
}

// ---- pack W[l][j][k][n] fp32 -> f16 B-frag layout (verified r1-r5)
__global__ __launch_bounds__(256) void pack_w(const float* __restrict__ W,
                                              _Float16* __restrict__ Wt2) {
  int tile = blockIdx.x;
  int m_idx = tile >> 8;            // 0..19  (= l*5+jj)
  int kt = (tile >> 4) & 15, ntt = tile & 15;
  int l = m_idx / 5, jj = m_idx % 5;
  const float* Wf = W + ((size_t)(l * 6 + jj + 1) << 20);
  _Float16* out = Wt2 + ((size_t)m_idx << 20);
  __shared__ float ts[64][65];
  int k0 = kt * 64, n0 = ntt * 64;
#pragma unroll
  for (int s = 0; s < 16; ++s) {
    int e = threadIdx.x + s * 256;
    int kk = e >> 6, col = e & 63;
    ts[kk][col] = Wf[(size_t)(k0 + kk) * H + n0 + col];
  }
  __syncthreads();
#pragma unroll
  for (int gi = 0; gi < 2; ++gi) {
    int g = threadIdx.x * 2 + gi;   // 0..511
    int l64 = g & 63, ksl = (g >> 6) & 1, ntl = g >> 7;
    int nn = l64 & 15, kh = l64 >> 4;
    half8 tmp;
#pragma unroll
    for (int e = 0; e < 8; ++e)
      tmp[e] = (_Float16)ts[ksl * 32 + kh * 8 + e][ntl * 16 + nn];
    *(half8*)&out[(size_t)((ntt * 4 + ntl) * 32 + kt * 2 + ksl) * 512 + (size_t)l64 * 8] = tmp;
  }
}

// ---- pack x fp32 -> f16 A-frag layout per t (verified r1-r5)
__global__ __launch_bounds__(256) void pack_x(const float* __restrict__ x,
                                              _Float16* __restrict__ x_pk) {
  int t = blockIdx.x;
  __shared__ float ld[32][257];
  for (int c = 0; c < 4; ++c) {
#pragma unroll
    for (int s = 0; s < 32; ++s) {
      int e2 = threadIdx.x + s * 256;
      int b = e2 >> 8, col = e2 & 255;
      ld[b][col] = x[((size_t)b * T + t) * H + c * 256 + col];
    }
    __syncthreads();
#pragma unroll
    for (int s3 = 0; s3 < 4; ++s3) {
      int gg = threadIdx.x * 4 + s3;  // 0..1023
      int l64 = gg & 63, ksl = (gg >> 6) & 7, bt = gg >> 9;
      int nn = l64 & 15, kh = l64 >> 4;
      int b = bt * 16 + nn;
      half8 tmp;
#pragma unroll
      for (int e = 0; e < 8; ++e)
        tmp[e] = (_Float16)ld[b][ksl * 32 + kh * 8 + e];
      *(half8*)&x_pk[(size_t)t * 32768 + (size_t)bt * 16384 +
                     (size_t)(c * 8 + ksl) * 512 + (size_t)l64 * 8] = tmp;
    }
    __syncthreads();
  }
}

// ---- once: per-layer sums of ln_g/ln_b for the k projection (j index 1)
__global__ __launch_bounds__(256) void gsum_kernel(
    const float* __restrict__ ln_g, const float* __restrict__ ln_b,
    float* __restrict__ gsums) {
  int l = blockIdx.x;
  int tid = threadIdx.x;
  float4 g4 = *(const float4*)&ln_g[(size_t)(l * 6 + 1) * H + tid * 4];
  float4 b4 = *(const float4*)&ln_b[(size_t)(l * 6 + 1) * H + tid * 4];
  float sg = g4.x + g4.y + g4.z + g4.w;
  float sb = b4.x + b4.y + b4.z + b4.w;
#pragma unroll
  for (int off = 32; off; off >>= 1) {
    sg += __shfl_down(sg, off);
    sb += __shfl_down(sb, off);
  }
  __shared__ float sm[8];
  if ((tid & 63) == 0) { sm[tid >> 6] = sg; sm[(tid >> 6) + 4] = sb; }
  __syncthreads();
  if (tid == 0) {
    gsums[l * 2]     = sm[0] + sm[1] + sm[2] + sm[3];
    gsums[l * 2 + 1] = sm[4] + sm[5] + sm[6] + sm[7];
  }
}

// ---- GEMM: block 128m x 256n, 8 waves (2wm x 4wn), wave 64m x 64n.
// global_load_lds staging (wave-uniform frag base + lane*16B), 1 barrier/K-step.
// Epilogue also emits per-row LN-stat partials (s, sq, sk) for this block's 256 cols.
__global__ __launch_bounds__(512) void gemm_big(
    const _Float16* __restrict__ A_pk, const _Float16* __restrict__ Wl,
    const float* __restrict__ bias, const float* __restrict__ ln_g,
    _Float16* __restrict__ z16, float* __restrict__ psum, int l, int t0) {
  int raw = blockIdx.x;
  int swz = (raw & 7) * 80 + (raw >> 3);   // 640 = 8 XCD x 80, bijective
  int bm = swz & 31;
  int bn = swz >> 5;
  int w = threadIdx.x >> 6, lane = threadIdx.x & 63;
  int wm = w >> 2, wn = w & 3;

  __shared__ _Float16 smem[24576];   // 2 x 12288; epilogue reuses as cz[64][264]

  int j = bn >> 2;
  // this wave's 3 staging frags (24 total: A f=0..7, B f=8..23)
  const _Float16* gsrc[3];
  int lbase[3];
#pragma unroll
  for (int q = 0; q < 3; ++q) {
    int f = w * 3 + q;
    if (f < 8) {
      gsrc[q] = A_pk + (size_t)(t0 * 2 + bm * 8 + f) * 16384 + lane * 8;
      lbase[q] = f * 512;
    } else {
      int nf = f - 8;
      gsrc[q] = Wl + ((size_t)j << 20) + (size_t)((bn & 3) * 16 + nf) * 16384 + lane * 8;
      lbase[q] = 4096 + nf * 512;
    }
  }

  // prologue: stage ks=0 into buffer 0
#pragma unroll
  for (int q = 0; q < 3; ++q) gll16(gsrc[q], &smem[lbase[q]]);
  __syncthreads();

  f32x4 acc[4][4] = {};
  int ardo = wm * 2048 + lane * 8;          // a-frag read base (within buffer)
  int brdo = 4096 + wn * 2048 + lane * 8;   // b-frag read base

  for (int ks = 0; ks < 32; ++ks) {
    int cur = (ks & 1) * 12288;
    int nxt = cur ^ 12288;
    if (ks + 1 < 32) {
#pragma unroll
      for (int q = 0; q < 3; ++q)
        gll16(gsrc[q] + (ks + 1) * 512, &smem[nxt + lbase[q]]);
    }
    half8 a[4], b[4];
#pragma unroll
    for (int i = 0; i < 4; ++i) a[i] = *(const half8*)&smem[cur + ardo + i * 512];
#pragma unroll
    for (int i = 0; i < 4; ++i) b[i] = *(const half8*)&smem[cur + brdo + i * 512];
#pragma unroll
    for (int i = 0; i < 4; ++i)
#pragma unroll
      for (int jf = 0; jf < 4; ++jf)
        acc[i][jf] = __builtin_amdgcn_mfma_f32_16x16x32_f16(a[i], b[jf], acc[i][jf], 0, 0, 0);
    __syncthreads();   // drains glld (vmcnt) + ds reads (lgkm)
  }

  // epilogue: stage C tile via LDS, store half8 rows, emit stat partials
  _Float16 (*cz)[264] = (_Float16(*)[264])smem;
  int hb0 = (bn & 3) * 256;
  for (int p = 0; p < 2; ++p) {
    if (p) __syncthreads();
    if (wm == p) {
#pragma unroll
      for (int i = 0; i < 4; ++i)
#pragma unroll
        for (int jf = 0; jf < 4; ++jf)
#pragma unroll
          for (int r = 0; r < 4; ++r)
            cz[i * 16 + (lane >> 4) * 4 + r][wn * 64 + jf * 16 + (lane & 15)] =
                (_Float16)acc[i][jf][r];
    }
    __syncthreads();
#pragma unroll
    for (int s = 0; s < 4; ++s) {
      int e = threadIdx.x + s * 512;
      int r = e >> 5, h8 = e & 31;
      int m_local = bm * 128 + p * 64 + r;
      half8 vv = *(const half8*)&cz[r][h8 * 8];
      *(half8*)&z16[((size_t)m_local * 5 + j) * 1024 + hb0 + h8 * 8] = vv;
    }
    // per-row partial sums over this block's 256 cols (8 threads per row)
    {
      int r = threadIdx.x >> 3;             // 0..63
      int c0 = (threadIdx.x & 7) * 32;
      int m_local = bm * 128 + p * 64 + r;
      const float* bp = bias + (size_t)(l * 6 + 1 + j) * H + hb0 + c0;
      const float* gp = ln_g + (size_t)(l * 6 + 1) * H + hb0 + c0;
      float s = 0.f, sq = 0.f, sk = 0.f;
#pragma unroll 8
      for (int ci = 0; ci < 32; ++ci) {
        float val = (float)cz[r][c0 + ci] + bp[ci];
        s += val;
        sq += val * val;
        if (j == 0) sk += val * gp[ci];
      }
#pragma unroll
      for (int off = 4; off; off >>= 1) {
        s  += __shfl_down(s, off, 8);
        sq += __shfl_down(sq, off, 8);
        sk += __shfl_down(sk, off, 8);
      }
      if ((threadIdx.x & 7) == 0)
        *(float4*)&psum[((size_t)bn * 4096 + m_local) * 4] =
            make_float4(s, sq, sk, 0.f);
    }
  }
}

// ---- combine per-bn partials -> stats rows [mu,rs]x5 + ksum
__global__ __launch_bounds__(256) void stats_finalize(
    const float* __restrict__ psum, const float* __restrict__ gsums,
    float* __restrict__ stats, int l) {
  int row = blockIdx.x * 256 + threadIdx.x;  // 4096
  float* so = stats + (size_t)row * 12;
  float mu0 = 0.f, rs0 = 0.f;
#pragma unroll
  for (int jj = 0; jj < 5; ++jj) {
    float s = 0.f, sq = 0.f;
#pragma unroll
    for (int q = 0; q < 4; ++q) {
      size_t off = ((size_t)(jj * 4 + q) * 4096 + row) * 4;
      s += psum[off];
      sq += psum[off + 1];
    }
    float mu = s * (1.0f / H);
    float var = sq * (1.0f / H) - mu * mu;
    float rs = rsqrtf(var + 1e-5f);
    so[jj * 2] = mu;
    so[jj * 2 + 1] = rs;
    if (jj == 0) { mu0 = mu; rs0 = rs; }
  }
  float sk = 0.f;
#pragma unroll
  for (int q = 0; q < 4; ++q)
    sk += psum[((size_t)q * 4096 + row) * 4 + 2];
  so[10] = rs0 * (sk - mu0 * gsums[l * 2]) + gsums[l * 2 + 1];
  so[11] = 0.f;
}

// ---- scan pass 1: per-segment local scans (verified r4/r5)
__global__ __launch_bounds__(256) void scan_p1(
    const _Float16* __restrict__ z16, const float* __restrict__ stats,
    const float* __restrict__ bias, const float* __restrict__ ln_g,
    const float* __restrict__ ln_b, float* __restrict__ Abuf,
    float* __restrict__ Bc, float* __restrict__ Bn, int l) {
  int idx = blockIdx.x * 256 + threadIdx.x;   // 262144 threads
  int h = idx & 1023;
  int bs = idx >> 10;
  int b = bs & 31, seg = bs >> 5;

  float bz[4], gg[4], bb[4];
#pragma unroll
  for (int jj = 0; jj < 4; ++jj) {
    bz[jj] = bias[(size_t)(l * 6 + 1 + jj) * H + h];
    gg[jj] = ln_g[(size_t)(l * 6 + 1 + jj) * H + h];
    bb[jj] = ln_b[(size_t)(l * 6 + 1 + jj) * H + h];
  }
  float A = 1.f, bc = 0.f, bn = 0.f;
#pragma unroll 2
  for (int u = 0; u < SEGLEN; ++u) {
    int row = (seg * SEGLEN + u) * 32 + b;
    size_t zb = ((size_t)row * 5) * 1024 + h;
    float zk = (float)z16[zb];
    float zv = (float)z16[zb + 1024];
    float zi = (float)z16[zb + 2048];
    float zf = (float)z16[zb + 3072];
    const float* st = stats + (size_t)row * 12;
    float k   = (zk + bz[0] - st[0]) * st[1] * gg[0] + bb[0];
    float v   = (zv + bz[1] - st[2]) * st[3] * gg[1] + bb[1];
    float zi_ = (zi + bz[2] - st[4]) * st[5] * gg[2] + bb[2];
    float zf_ = (zf + bz[3] - st[6]) * st[7] * gg[3] + bb[3];
    float iv = __expf(zi_);
    float fv = 1.f / (1.f + __expf(-zf_));
    A *= fv;
    bn = fv * bn + iv * k;
    bc = fv * bc + iv * (st[10] * v);
    size_t o = (size_t)row * 1024 + h;
    Abuf[o] = A;
    Bn[o] = bn;
    Bc[o] = bc;
  }
}

// ---- scan pass 2: carry-in per segment (verified r4/r5)
__global__ __launch_bounds__(256) void scan_p2(
    const float* __restrict__ Abuf, const float* __restrict__ Bc,
    const float* __restrict__ Bn, float* __restrict__ state,
    float* __restrict__ carC, float* __restrict__ carN, int l, int t0) {
  int idx = blockIdx.x * 256 + threadIdx.x;   // 32768
  int h = idx & 1023, b = idx >> 10;
  size_t sidx = ((size_t)l * B + b) * H + h;
  float cc = 0.f, nn = 0.f;
  if (t0 > 0) {
    cc = state[sidx];
    nn = state[(size_t)L * B * H + sidx];
  }
#pragma unroll
  for (int seg = 0; seg < NSEG; ++seg) {
    size_t coff = (size_t)seg * 32768 + (size_t)b * 1024 + h;
    carC[coff] = cc;
    carN[coff] = nn;
    int rowLast = (seg * SEGLEN + SEGLEN - 1) * 32 + b;
    size_t o = (size_t)rowLast * 1024 + h;
    float a = Abuf[o];
    cc = Bc[o] + a * cc;
    nn = Bn[o] + a * nn;
  }
  state[sidx] = cc;
  state[(size_t)L * B * H + sidx] = nn;
}

// ---- final (verified r4/r5)
__global__ __launch_bounds__(256) void final_kernel(
    const _Float16* __restrict__ z16, const float* __restrict__ stats,
    const float* __restrict__ bias, const float* __restrict__ ln_g,
    const float* __restrict__ ln_b, const float* __restrict__ Abuf,
    const float* __restrict__ Bc, const float* __restrict__ Bn,
    const float* __restrict__ carC, const float* __restrict__ carN,
    const _Float16* __restrict__ hin, _Float16* __restrict__ hout,
    float* __restrict__ out, int l, int t0) {
  int row = blockIdx.x;
  int b = row & 31, tc = row >> 5, t = t0 + tc, seg = tc / SEGLEN;
  int tid = threadIdx.x, h0 = tid * 4;
  size_t o = (size_t)row * 1024 + h0;
  size_t coff = (size_t)seg * 32768 + (size_t)b * 1024 + h0;
  float4 a4 = *(const float4*)&Abuf[o];
  float4 bn4 = *(const float4*)&Bn[o];
  float4 bc4 = *(const float4*)&Bc[o];
  float4 cN = *(const float4*)&carN[coff];
  float4 cC = *(const float4*)&carC[coff];
  float nn[4] = {bn4.x + a4.x * cN.x, bn4.y + a4.y * cN.y,
                 bn4.z + a4.z * cN.z, bn4.w + a4.w * cN.w};
  float cc[4] = {bc4.x + a4.x * cC.x, bc4.y + a4.y * cC.y,
                 bc4.z + a4.z * cC.z, bc4.w + a4.w * cC.w};

  float ss = nn[0] * nn[0] + nn[1] * nn[1] + nn[2] * nn[2] + nn[3] * nn[3];
#pragma unroll
  for (int off = 32; off; off >>= 1) ss += __shfl_down(ss, off);
  __shared__ float sb[4];
  if ((tid & 63) == 0) sb[tid >> 6] = ss;
  __syncthreads();
  float rn = 1.f / (sqrtf(sb[0] + sb[1] + sb[2] + sb[3]) + 1e-8f);

  half4 zo4 = *(const half4*)&z16[((size_t)row * 5 + 4) * 1024 + h0];
  const float* st = stats + (size_t)row * 12;
  float mu = st[8], rs = st[9];
  float4 bz = *(const float4*)&bias[(size_t)(l * 6 + 5) * H + h0];
  float4 g4 = *(const float4*)&ln_g[(size_t)(l * 6 + 5) * H + h0];
  float4 be4 = *(const float4*)&ln_b[(size_t)(l * 6 + 5) * H + h0];
  float gv[4] = {g4.x, g4.y, g4.z, g4.w};
  float bev[4] = {be4.x, be4.y, be4.z, be4.w};
  float zov[4] = {(float)zo4[0] + bz.x, (float)zo4[1] + bz.y,
                  (float)zo4[2] + bz.z, (float)zo4[3] + bz.w};

  size_t hfoff = (size_t)(b >> 4) * 16384 + (size_t)(h0 >> 5) * 512 +
                 (size_t)((((h0 & 31) >> 3) * 16) + (b & 15)) * 8 + (h0 & 7);
  half4 rin;
  if (l > 0) rin = *(const half4*)&hin[(size_t)t * 32768 + hfoff];

  float hh[4];
#pragma unroll
  for (int u = 0; u < 4; ++u) {
    float ov = 1.f / (1.f + __expf(-((zov[u] - mu) * rs * gv[u] + bev[u])));
    float targ = cc[u] * (nn[u] * rn);
    float e2 = __expf(-2.f * fabsf(targ));
    float th = copysignf((1.f - e2) / (1.f + e2), targ);
    hh[u] = ov * th + ((l > 0) ? (float)rin[u] : 0.f);
  }
  half4 hx;
  hx[0] = (_Float16)hh[0]; hx[1] = (_Float16)hh[1];
  hx[2] = (_Float16)hh[2]; hx[3] = (_Float16)hh[3];
  *(half4*)&hout[(size_t)t * 32768 + hfoff] = hx;

  if (t == T - 1) {
    *(float4*)&out[8192 + (size_t)l * 32768 + (size_t)b * 1024 + h0] =
        make_float4(hh[0], hh[1], hh[2], hh[3]);
    *(float4*)&out[8192 + 131072 + ((size_t)(l * B) + b) * 1024 + h0] =
        make_float4(cc[0], cc[1], cc[2], cc[3]);
    *(float4*)&out[8192 + 262144 + ((size_t)(l * B) + b) * 1024 + h0] =
        make_float4(nn[0], nn[1], nn[2], nn[3]);
  }
}

// ---- fc: split-K partials + reduce (verified r4/r5)
__global__ __launch_bounds__(256) void fc_part(
    const float* __restrict__ out_h, const float* __restrict__ fc_w,
    float* __restrict__ partial) {
  int b = blockIdx.x >> 3, kh = blockIdx.x & 7;
  int o = threadIdx.x;
  const float* hr = out_h + (size_t)b * 1024 + kh * 128;
  const float* wp = fc_w + (size_t)kh * 128 * O + o;
  float acc = 0.f;
#pragma unroll 8
  for (int h = 0; h < 128; ++h)
    acc = fmaf(hr[h], wp[(size_t)h * O], acc);
  partial[((size_t)kh * 32 + b) * O + o] = acc;
}

__global__ __launch_bounds__(256) void fc_reduce(
    const float* __restrict__ partial, const float* __restrict__ fc_b,
    float* __restrict__ out) {
  int b = blockIdx.x, o = threadIdx.x;
  float acc = fc_b[o];
#pragma unroll
  for (int kh = 0; kh < 8; ++kh)
    acc += partial[((size_t)kh * 32 + b) * O + o];
  out[(size_t)b * O + o] = acc;
}

extern "C" void kernel_launch(void* const* d_in, const int* in_sizes, int n_in,
                              void* d_out, int out_size, void* d_ws, size_t ws_size,
                              hipStream_t stream) {
  const float* x    = (const float*)d_in[0];
  const float* W    = (const float*)d_in[1];
  const float* bias = (const float*)d_in[2];
  const float* ln_g = (const float*)d_in[3];
  const float* ln_b = (const float*)d_in[4];
  const float* fc_w = (const float*)d_in[5];
  const float* fc_b = (const float*)d_in[6];
  float* out = (float*)d_out;
  _Float16* wsh = (_Float16*)d_ws;

  _Float16* x_pk = wsh + X_PK_OFF;
  _Float16* hb[2] = {wsh + HB0_OFF, wsh + HB1_OFF};
  _Float16* Wt2  = wsh + WT2_OFF;
  _Float16* z16  = wsh + Z16_OFF;
  float* Abuf  = (float*)(wsh + A_OFF);
  float* Bc    = (float*)(wsh + BC_OFF);
  float* Bn    = (float*)(wsh + BN_OFF);
  float* stats = (float*)(wsh + STATS_OFF);
  float* carC  = (float*)(wsh + CARC_OFF);
  float* carN  = (float*)(wsh + CARN_OFF);
  float* state = (float*)(wsh + STATE_OFF);
  float* fcp   = (float*)(wsh + FCP_OFF);
  float* psum  = (float*)(wsh + PSUM_OFF);
  float* gsums = (float*)(wsh + GSUM_OFF);

  pack_w<<<5120, 256, 0, stream>>>(W, Wt2);
  pack_x<<<256, 256, 0, stream>>>(x, x_pk);
  gsum_kernel<<<4, 256, 0, stream>>>(ln_g, ln_b, gsums);

  for (int l = 0; l < L; ++l) {
    const _Float16* A_in = (l == 0) ? x_pk : hb[(l - 1) & 1];
    _Float16* h_out = hb[l & 1];
    const _Float16* Wl = Wt2 + ((size_t)(l * 5) << 20);
    for (int c = 0; c < NCHUNK; ++c) {
      int t0 = c * TCH;
      gemm_big<<<640, 512, 0, stream>>>(A_in, Wl, bias, ln_g, z16, psum, l, t0);
      stats_finalize<<<16, 256, 0, stream>>>(psum, gsums, stats, l);
      scan_p1<<<1024, 256, 0, stream>>>(z16, stats, bias, ln_g, ln_b,
                                        Abuf, Bc, Bn, l);
      scan_p2<<<128, 256, 0, stream>>>(Abuf, Bc, Bn, state, carC, carN, l, t0);
      final_kernel<<<4096, 256, 0, stream>>>(z16, stats, bias, ln_g, ln_b,
                                             Abuf, Bc, Bn, carC, carN,
                                             A_in, h_out, out, l, t0);
    }
  }
  fc_part<<<256, 256, 0, stream>>>(out + 8192 + 3 * 32768, fc_w, fcp);
  fc_reduce<<<B, 256, 0, stream>>>(fcp, fc_b, out);
}

// Round 8
// 965.774 us; speedup vs baseline: 1.1126x; 1.1126x over previous
//
#include <hip/hip_runtime.h>
#include <hip/hip_bf16.h>
#include <math.h>

#define H 1024
#define B 32
#define T 256
#define L 4
#define O 256
#define TCH 128        // time chunk
#define NCHUNK 2
#define SEGLEN 16
#define NSEG (TCH / SEGLEN)   // 8

typedef _Float16 half8 __attribute__((ext_vector_type(8)));
typedef _Float16 half4 __attribute__((ext_vector_type(4)));
typedef float f32x4 __attribute__((ext_vector_type(4)));

// ws layout (offsets in halves):
#define X_PK_OFF   0            // 8,388,608 halves (T*32 rows, A-frag f16)
#define HB0_OFF    8388608
#define HB1_OFF    16777216
#define WT2_OFF    25165824     // 20,971,520 halves
#define Z16_OFF    46137344     // 20,971,520 halves (chunk: 4096 rows x 5 x 1024 f16)
#define A_OFF      67108864     // 8,388,608 halves = 4096x1024 f32 (prefix prod of f)
#define BC_OFF     75497472     // 8,388,608 halves (local c-scan)
#define BN_OFF     83886080     // 8,388,608 halves (local n-scan)
#define STATS_OFF  92274688     // 98,304 halves = 4096x12 f32
#define CARC_OFF   92372992     // 524,288 halves = 8x32768 f32
#define CARN_OFF   92897280     // 524,288 halves
#define STATE_OFF  93421568     // 524,288 halves = 2*L*B*H f32
#define FCP_OFF    93945856     // 131,072 halves = 65536 f32
// total ~188 MB

// ---- pack W[l][j][k][n] fp32 -> f16 B-frag layout (verified r1-r6)
__global__ __launch_bounds__(256) void pack_w(const float* __restrict__ W,
                                              _Float16* __restrict__ Wt2) {
  int tile = blockIdx.x;
  int m_idx = tile >> 8;            // 0..19  (= l*5+jj)
  int kt = (tile >> 4) & 15, ntt = tile & 15;
  int l = m_idx / 5, jj = m_idx % 5;
  const float* Wf = W + ((size_t)(l * 6 + jj + 1) << 20);
  _Float16* out = Wt2 + ((size_t)m_idx << 20);
  __shared__ float ts[64][65];
  int k0 = kt * 64, n0 = ntt * 64;
#pragma unroll
  for (int s = 0; s < 16; ++s) {
    int e = threadIdx.x + s * 256;
    int kk = e >> 6, col = e & 63;
    ts[kk][col] = Wf[(size_t)(k0 + kk) * H + n0 + col];
  }
  __syncthreads();
#pragma unroll
  for (int gi = 0; gi < 2; ++gi) {
    int g = threadIdx.x * 2 + gi;   // 0..511
    int l64 = g & 63, ksl = (g >> 6) & 1, ntl = g >> 7;
    int nn = l64 & 15, kh = l64 >> 4;
    half8 tmp;
#pragma unroll
    for (int e = 0; e < 8; ++e)
      tmp[e] = (_Float16)ts[ksl * 32 + kh * 8 + e][ntl * 16 + nn];
    *(half8*)&out[(size_t)((ntt * 4 + ntl) * 32 + kt * 2 + ksl) * 512 + (size_t)l64 * 8] = tmp;
  }
}

// ---- pack x fp32 -> f16 A-frag layout per t (verified r1-r6)
__global__ __launch_bounds__(256) void pack_x(const float* __restrict__ x,
                                              _Float16* __restrict__ x_pk) {
  int t = blockIdx.x;
  __shared__ float ld[32][257];
  for (int c = 0; c < 4; ++c) {
#pragma unroll
    for (int s = 0; s < 32; ++s) {
      int e2 = threadIdx.x + s * 256;
      int b = e2 >> 8, col = e2 & 255;
      ld[b][col] = x[((size_t)b * T + t) * H + c * 256 + col];
    }
    __syncthreads();
#pragma unroll
    for (int s3 = 0; s3 < 4; ++s3) {
      int gg = threadIdx.x * 4 + s3;  // 0..1023
      int l64 = gg & 63, ksl = (gg >> 6) & 7, bt = gg >> 9;
      int nn = l64 & 15, kh = l64 >> 4;
      int b = bt * 16 + nn;
      half8 tmp;
#pragma unroll
      for (int e = 0; e < 8; ++e)
        tmp[e] = (_Float16)ld[b][ksl * 32 + kh * 8 + e];
      *(half8*)&x_pk[(size_t)t * 32768 + (size_t)bt * 16384 +
                     (size_t)(c * 8 + ksl) * 512 + (size_t)l64 * 8] = tmp;
    }
    __syncthreads();
  }
}

// ---- GEMM: block 128m x 256n, 8 waves (2wm x 4wn), wave 64m x 64n.
// Reg-staged LDS double buffer (r5-verified), ONE barrier per K-step:
// iteration ks reads cur, writes nxt; nxt's prior readers retired at the
// end-of-(ks-1) barrier (lgkmcnt drains before s_barrier), so the mid-loop
// barrier r5 had is redundant.
__global__ __launch_bounds__(512) void gemm_big(
    const _Float16* __restrict__ A_pk, const _Float16* __restrict__ Wl,
    _Float16* __restrict__ z16, int t0) {
  int raw = blockIdx.x;
  int swz = (raw & 7) * 80 + (raw >> 3);   // 640 = 8 XCD x 80, bijective
  int bm = swz & 31;
  int bn = swz >> 5;
  int w = threadIdx.x >> 6, lane = threadIdx.x & 63;
  int wm = w >> 2, wn = w & 3;

  __shared__ _Float16 smem[24576];   // 2 x 12288; epilogue reuses as cz[64][264]

  int j = bn >> 2;
  // this wave's 3 staging frags (24 total: A f=0..7, B f=8..23)
  const _Float16* gsrc[3];
  int ldst[3];
#pragma unroll
  for (int q = 0; q < 3; ++q) {
    int f = w * 3 + q;
    if (f < 8) {
      gsrc[q] = A_pk + (size_t)(t0 * 2 + bm * 8 + f) * 16384 + lane * 8;
      ldst[q] = f * 512 + lane * 8;
    } else {
      int nf = f - 8;
      gsrc[q] = Wl + ((size_t)j << 20) + (size_t)((bn & 3) * 16 + nf) * 16384 + lane * 8;
      ldst[q] = 4096 + nf * 512 + lane * 8;
    }
  }

  // prologue: stage ks=0 into buffer 0
  half8 st[3];
#pragma unroll
  for (int q = 0; q < 3; ++q) st[q] = *(const half8*)(gsrc[q]);
#pragma unroll
  for (int q = 0; q < 3; ++q) *(half8*)&smem[ldst[q]] = st[q];
  __syncthreads();

  f32x4 acc[4][4] = {};
  int ardo = wm * 2048 + lane * 8;          // a-frag read base (within buffer)
  int brdo = 4096 + wn * 2048 + lane * 8;   // b-frag read base

  for (int ks = 0; ks < 32; ++ks) {
    int cur = (ks & 1) * 12288;
    // prefetch next K-step into regs (latency overlaps the MFMA block)
    if (ks + 1 < 32) {
#pragma unroll
      for (int q = 0; q < 3; ++q) st[q] = *(const half8*)(gsrc[q] + (ks + 1) * 512);
    }
    half8 a[4], b[4];
#pragma unroll
    for (int i = 0; i < 4; ++i) a[i] = *(const half8*)&smem[cur + ardo + i * 512];
#pragma unroll
    for (int i = 0; i < 4; ++i) b[i] = *(const half8*)&smem[cur + brdo + i * 512];
#pragma unroll
    for (int i = 0; i < 4; ++i)
#pragma unroll
      for (int jf = 0; jf < 4; ++jf)
        acc[i][jf] = __builtin_amdgcn_mfma_f32_16x16x32_f16(a[i], b[jf], acc[i][jf], 0, 0, 0);
    if (ks + 1 < 32) {
#pragma unroll
      for (int q = 0; q < 3; ++q) *(half8*)&smem[(cur ^ 12288) + ldst[q]] = st[q];
    }
    __syncthreads();   // single barrier: nxt-writes visible before next reads
  }

  // epilogue (verified r3-r5): stage C tile via LDS, store half8 rows
  _Float16 (*cz)[264] = (_Float16(*)[264])smem;
  int hb0 = (bn & 3) * 256;
  for (int p = 0; p < 2; ++p) {
    if (p) __syncthreads();
    if (wm == p) {
#pragma unroll
      for (int i = 0; i < 4; ++i)
#pragma unroll
        for (int jf = 0; jf < 4; ++jf)
#pragma unroll
          for (int r = 0; r < 4; ++r)
            cz[i * 16 + (lane >> 4) * 4 + r][wn * 64 + jf * 16 + (lane & 15)] =
                (_Float16)acc[i][jf][r];
    }
    __syncthreads();
#pragma unroll
    for (int s = 0; s < 4; ++s) {
      int e = threadIdx.x + s * 512;
      int r = e >> 5, h8 = e & 31;
      int m_local = bm * 128 + p * 64 + r;
      half8 vv = *(const half8*)&cz[r][h8 * 8];
      *(half8*)&z16[((size_t)m_local * 5 + j) * 1024 + hb0 + h8 * 8] = vv;
    }
  }
}

// ---- per-row LN stats + ksum (verified r3-r5)
__global__ __launch_bounds__(256) void stats_kernel(
    const _Float16* __restrict__ z16, const float* __restrict__ bias,
    const float* __restrict__ ln_g, const float* __restrict__ ln_b,
    float* __restrict__ stats, int l) {
  int row = blockIdx.x, tid = threadIdx.x;
  int h0 = tid * 4;
  float red[13];
#pragma unroll
  for (int jj = 0; jj < 5; ++jj) {
    half4 z4 = *(const half4*)&z16[((size_t)row * 5 + jj) * 1024 + h0];
    float4 bb = *(const float4*)&bias[(size_t)(l * 6 + 1 + jj) * H + h0];
    float vx = (float)z4[0] + bb.x, vy = (float)z4[1] + bb.y,
          vz = (float)z4[2] + bb.z, vw = (float)z4[3] + bb.w;
    red[jj * 2] = vx + vy + vz + vw;
    red[jj * 2 + 1] = vx * vx + vy * vy + vz * vz + vw * vw;
    if (jj == 0) {
      float4 g = *(const float4*)&ln_g[(size_t)(l * 6 + 1) * H + h0];
      float4 be = *(const float4*)&ln_b[(size_t)(l * 6 + 1) * H + h0];
      red[10] = vx * g.x + vy * g.y + vz * g.z + vw * g.w;
      red[11] = g.x + g.y + g.z + g.w;
      red[12] = be.x + be.y + be.z + be.w;
    }
  }
#pragma unroll
  for (int off = 32; off; off >>= 1)
#pragma unroll
    for (int q = 0; q < 13; ++q) red[q] += __shfl_down(red[q], off);
  __shared__ float sb[4][13];
  if ((tid & 63) == 0) {
#pragma unroll
    for (int q = 0; q < 13; ++q) sb[tid >> 6][q] = red[q];
  }
  __syncthreads();
  if (tid == 0) {
    float st[13];
#pragma unroll
    for (int q = 0; q < 13; ++q) st[q] = sb[0][q] + sb[1][q] + sb[2][q] + sb[3][q];
    float* so = stats + (size_t)row * 12;
#pragma unroll
    for (int jj = 0; jj < 5; ++jj) {
      float mu = st[jj * 2] * (1.0f / H);
      float var = st[jj * 2 + 1] * (1.0f / H) - mu * mu;
      so[jj * 2] = mu;
      so[jj * 2 + 1] = rsqrtf(var + 1e-5f);
    }
    float mu0 = st[0] * (1.0f / H);
    float rs0 = rsqrtf(st[1] * (1.0f / H) - mu0 * mu0 + 1e-5f);
    so[10] = rs0 * (st[10] - mu0 * st[11]) + st[12];
    so[11] = 0.f;
  }
}

// ---- scan pass 1: per-segment local scans, vectorized x4 over h.
// thread = (seg,b, h-quad); one wave is (seg,b)-uniform -> stats loads broadcast.
__global__ __launch_bounds__(256) void scan_p1(
    const _Float16* __restrict__ z16, const float* __restrict__ stats,
    const float* __restrict__ bias, const float* __restrict__ ln_g,
    const float* __restrict__ ln_b, float* __restrict__ Abuf,
    float* __restrict__ Bc, float* __restrict__ Bn, int l) {
  int idx = blockIdx.x * 256 + threadIdx.x;   // 65536 threads
  int h0 = (idx & 255) * 4;
  int bs = idx >> 8;
  int b = bs & 31, seg = bs >> 5;

  float bz[4][4], gg[4][4], bb[4][4];
#pragma unroll
  for (int jj = 0; jj < 4; ++jj) {
    float4 t1 = *(const float4*)&bias[(size_t)(l * 6 + 1 + jj) * H + h0];
    float4 t2 = *(const float4*)&ln_g[(size_t)(l * 6 + 1 + jj) * H + h0];
    float4 t3 = *(const float4*)&ln_b[(size_t)(l * 6 + 1 + jj) * H + h0];
    bz[jj][0] = t1.x; bz[jj][1] = t1.y; bz[jj][2] = t1.z; bz[jj][3] = t1.w;
    gg[jj][0] = t2.x; gg[jj][1] = t2.y; gg[jj][2] = t2.z; gg[jj][3] = t2.w;
    bb[jj][0] = t3.x; bb[jj][1] = t3.y; bb[jj][2] = t3.z; bb[jj][3] = t3.w;
  }
  float A[4] = {1.f, 1.f, 1.f, 1.f};
  float bc[4] = {0.f, 0.f, 0.f, 0.f};
  float bn[4] = {0.f, 0.f, 0.f, 0.f};
#pragma unroll 2
  for (int u = 0; u < SEGLEN; ++u) {
    int row = (seg * SEGLEN + u) * 32 + b;
    size_t zb = ((size_t)row * 5) * 1024 + h0;
    half4 zk4 = *(const half4*)&z16[zb];
    half4 zv4 = *(const half4*)&z16[zb + 1024];
    half4 zi4 = *(const half4*)&z16[zb + 2048];
    half4 zf4 = *(const half4*)&z16[zb + 3072];
    const float* st = stats + (size_t)row * 12;   // wave-uniform
    float mu0 = st[0], rs0 = st[1], mu1 = st[2], rs1 = st[3];
    float mu2 = st[4], rs2 = st[5], mu3 = st[6], rs3 = st[7];
    float ksum = st[10];
#pragma unroll
    for (int e = 0; e < 4; ++e) {
      float k   = ((float)zk4[e] + bz[0][e] - mu0) * rs0 * gg[0][e] + bb[0][e];
      float v   = ((float)zv4[e] + bz[1][e] - mu1) * rs1 * gg[1][e] + bb[1][e];
      float zi_ = ((float)zi4[e] + bz[2][e] - mu2) * rs2 * gg[2][e] + bb[2][e];
      float zf_ = ((float)zf4[e] + bz[3][e] - mu3) * rs3 * gg[3][e] + bb[3][e];
      float iv = __expf(zi_);
      float fv = 1.f / (1.f + __expf(-zf_));
      A[e] *= fv;
      bn[e] = fv * bn[e] + iv * k;
      bc[e] = fv * bc[e] + iv * (ksum * v);
    }
    size_t o = (size_t)row * 1024 + h0;
    *(float4*)&Abuf[o] = make_float4(A[0], A[1], A[2], A[3]);
    *(float4*)&Bn[o]   = make_float4(bn[0], bn[1], bn[2], bn[3]);
    *(float4*)&Bc[o]   = make_float4(bc[0], bc[1], bc[2], bc[3]);
  }
}

// ---- scan pass 2: carry-in per segment (verified r4/r5)
__global__ __launch_bounds__(256) void scan_p2(
    const float* __restrict__ Abuf, const float* __restrict__ Bc,
    const float* __restrict__ Bn, float* __restrict__ state,
    float* __restrict__ carC, float* __restrict__ carN, int l, int t0) {
  int idx = blockIdx.x * 256 + threadIdx.x;   // 32768
  int h = idx & 1023, b = idx >> 10;
  size_t sidx = ((size_t)l * B + b) * H + h;
  float cc = 0.f, nn = 0.f;
  if (t0 > 0) {
    cc = state[sidx];
    nn = state[(size_t)L * B * H + sidx];
  }
#pragma unroll
  for (int seg = 0; seg < NSEG; ++seg) {
    size_t coff = (size_t)seg * 32768 + (size_t)b * 1024 + h;
    carC[coff] = cc;
    carN[coff] = nn;
    int rowLast = (seg * SEGLEN + SEGLEN - 1) * 32 + b;
    size_t o = (size_t)rowLast * 1024 + h;
    float a = Abuf[o];
    cc = Bc[o] + a * cc;
    nn = Bn[o] + a * nn;
  }
  state[sidx] = cc;
  state[(size_t)L * B * H + sidx] = nn;
}

// ---- final (verified r4/r5)
__global__ __launch_bounds__(256) void final_kernel(
    const _Float16* __restrict__ z16, const float* __restrict__ stats,
    const float* __restrict__ bias, const float* __restrict__ ln_g,
    const float* __restrict__ ln_b, const float* __restrict__ Abuf,
    const float* __restrict__ Bc, const float* __restrict__ Bn,
    const float* __restrict__ carC, const float* __restrict__ carN,
    const _Float16* __restrict__ hin, _Float16* __restrict__ hout,
    float* __restrict__ out, int l, int t0) {
  int row = blockIdx.x;
  int b = row & 31, tc = row >> 5, t = t0 + tc, seg = tc / SEGLEN;
  int tid = threadIdx.x, h0 = tid * 4;
  size_t o = (size_t)row * 1024 + h0;
  size_t coff = (size_t)seg * 32768 + (size_t)b * 1024 + h0;
  float4 a4 = *(const float4*)&Abuf[o];
  float4 bn4 = *(const float4*)&Bn[o];
  float4 bc4 = *(const float4*)&Bc[o];
  float4 cN = *(const float4*)&carN[coff];
  float4 cC = *(const float4*)&carC[coff];
  float nn[4] = {bn4.x + a4.x * cN.x, bn4.y + a4.y * cN.y,
                 bn4.z + a4.z * cN.z, bn4.w + a4.w * cN.w};
  float cc[4] = {bc4.x + a4.x * cC.x, bc4.y + a4.y * cC.y,
                 bc4.z + a4.z * cC.z, bc4.w + a4.w * cC.w};

  float ss = nn[0] * nn[0] + nn[1] * nn[1] + nn[2] * nn[2] + nn[3] * nn[3];
#pragma unroll
  for (int off = 32; off; off >>= 1) ss += __shfl_down(ss, off);
  __shared__ float sb[4];
  if ((tid & 63) == 0) sb[tid >> 6] = ss;
  __syncthreads();
  float rn = 1.f / (sqrtf(sb[0] + sb[1] + sb[2] + sb[3]) + 1e-8f);

  half4 zo4 = *(const half4*)&z16[((size_t)row * 5 + 4) * 1024 + h0];
  const float* st = stats + (size_t)row * 12;
  float mu = st[8], rs = st[9];
  float4 bz = *(const float4*)&bias[(size_t)(l * 6 + 5) * H + h0];
  float4 g4 = *(const float4*)&ln_g[(size_t)(l * 6 + 5) * H + h0];
  float4 be4 = *(const float4*)&ln_b[(size_t)(l * 6 + 5) * H + h0];
  float gv[4] = {g4.x, g4.y, g4.z, g4.w};
  float bev[4] = {be4.x, be4.y, be4.z, be4.w};
  float zov[4] = {(float)zo4[0] + bz.x, (float)zo4[1] + bz.y,
                  (float)zo4[2] + bz.z, (float)zo4[3] + bz.w};

  size_t hfoff = (size_t)(b >> 4) * 16384 + (size_t)(h0 >> 5) * 512 +
                 (size_t)((((h0 & 31) >> 3) * 16) + (b & 15)) * 8 + (h0 & 7);
  half4 rin;
  if (l > 0) rin = *(const half4*)&hin[(size_t)t * 32768 + hfoff];

  float hh[4];
#pragma unroll
  for (int u = 0; u < 4; ++u) {
    float ov = 1.f / (1.f + __expf(-((zov[u] - mu) * rs * gv[u] + bev[u])));
    float targ = cc[u] * (nn[u] * rn);
    float e2 = __expf(-2.f * fabsf(targ));
    float th = copysignf((1.f - e2) / (1.f + e2), targ);
    hh[u] = ov * th + ((l > 0) ? (float)rin[u] : 0.f);
  }
  half4 hx;
  hx[0] = (_Float16)hh[0]; hx[1] = (_Float16)hh[1];
  hx[2] = (_Float16)hh[2]; hx[3] = (_Float16)hh[3];
  *(half4*)&hout[(size_t)t * 32768 + hfoff] = hx;

  if (t == T - 1) {
    *(float4*)&out[8192 + (size_t)l * 32768 + (size_t)b * 1024 + h0] =
        make_float4(hh[0], hh[1], hh[2], hh[3]);
    *(float4*)&out[8192 + 131072 + ((size_t)(l * B) + b) * 1024 + h0] =
        make_float4(cc[0], cc[1], cc[2], cc[3]);
    *(float4*)&out[8192 + 262144 + ((size_t)(l * B) + b) * 1024 + h0] =
        make_float4(nn[0], nn[1], nn[2], nn[3]);
  }
}

// ---- fc: split-K partials + reduce (verified r4/r5)
__global__ __launch_bounds__(256) void fc_part(
    const float* __restrict__ out_h, const float* __restrict__ fc_w,
    float* __restrict__ partial) {
  int b = blockIdx.x >> 3, kh = blockIdx.x & 7;
  int o = threadIdx.x;
  const float* hr = out_h + (size_t)b * 1024 + kh * 128;
  const float* wp = fc_w + (size_t)kh * 128 * O + o;
  float acc = 0.f;
#pragma unroll 8
  for (int h = 0; h < 128; ++h)
    acc = fmaf(hr[h], wp[(size_t)h * O], acc);
  partial[((size_t)kh * 32 + b) * O + o] = acc;
}

__global__ __launch_bounds__(256) void fc_reduce(
    const float* __restrict__ partial, const float* __restrict__ fc_b,
    float* __restrict__ out) {
  int b = blockIdx.x, o = threadIdx.x;
  float acc = fc_b[o];
#pragma unroll
  for (int kh = 0; kh < 8; ++kh)
    acc += partial[((size_t)kh * 32 + b) * O + o];
  out[(size_t)b * O + o] = acc;
}

extern "C" void kernel_launch(void* const* d_in, const int* in_sizes, int n_in,
                              void* d_out, int out_size, void* d_ws, size_t ws_size,
                              hipStream_t stream) {
  const float* x    = (const float*)d_in[0];
  const float* W    = (const float*)d_in[1];
  const float* bias = (const float*)d_in[2];
  const float* ln_g = (const float*)d_in[3];
  const float* ln_b = (const float*)d_in[4];
  const float* fc_w = (const float*)d_in[5];
  const float* fc_b = (const float*)d_in[6];
  float* out = (float*)d_out;
  _Float16* wsh = (_Float16*)d_ws;

  _Float16* x_pk = wsh + X_PK_OFF;
  _Float16* hb[2] = {wsh + HB0_OFF, wsh + HB1_OFF};
  _Float16* Wt2  = wsh + WT2_OFF;
  _Float16* z16  = wsh + Z16_OFF;
  float* Abuf  = (float*)(wsh + A_OFF);
  float* Bc    = (float*)(wsh + BC_OFF);
  float* Bn    = (float*)(wsh + BN_OFF);
  float* stats = (float*)(wsh + STATS_OFF);
  float* carC  = (float*)(wsh + CARC_OFF);
  float* carN  = (float*)(wsh + CARN_OFF);
  float* state = (float*)(wsh + STATE_OFF);
  float* fcp   = (float*)(wsh + FCP_OFF);

  pack_w<<<5120, 256, 0, stream>>>(W, Wt2);
  pack_x<<<256, 256, 0, stream>>>(x, x_pk);

  for (int l = 0; l < L; ++l) {
    const _Float16* A_in = (l == 0) ? x_pk : hb[(l - 1) & 1];
    _Float16* h_out = hb[l & 1];
    const _Float16* Wl = Wt2 + ((size_t)(l * 5) << 20);
    for (int c = 0; c < NCHUNK; ++c) {
      int t0 = c * TCH;
      gemm_big<<<640, 512, 0, stream>>>(A_in, Wl, z16, t0);
      stats_kernel<<<4096, 256, 0, stream>>>(z16, bias, ln_g, ln_b, stats, l);
      scan_p1<<<256, 256, 0, stream>>>(z16, stats, bias, ln_g, ln_b,
                                       Abuf, Bc, Bn, l);
      scan_p2<<<128, 256, 0, stream>>>(Abuf, Bc, Bn, state, carC, carN, l, t0);
      final_kernel<<<4096, 256, 0, stream>>>(z16, stats, bias, ln_g, ln_b,
                                             Abuf, Bc, Bn, carC, carN,
                                             A_in, h_out, out, l, t0);
    }
  }
  fc_part<<<256, 256, 0, stream>>>(out + 8192 + 3 * 32768, fc_w, fcp);
  fc_reduce<<<B, 256, 0, stream>>>(fcp, fc_b, out);
}

// Round 9
// 893.880 us; speedup vs baseline: 1.2021x; 1.0804x over previous
//
#include <hip/hip_runtime.h>
#include <hip/hip_bf16.h>
#include <math.h>

#define H 1024
#define B 32
#define T 256
#define L 4
#define O 256
#define TCH 128        // time chunk
#define NCHUNK 2
#define SEGLEN 16
#define NSEG (TCH / SEGLEN)   // 8

typedef _Float16 half8 __attribute__((ext_vector_type(8)));
typedef _Float16 half4 __attribute__((ext_vector_type(4)));
typedef float f32x4 __attribute__((ext_vector_type(4)));

// ws layout (offsets in halves):
#define X_PK_OFF   0            // 8,388,608 halves (T*32 rows, A-frag f16)
#define HB0_OFF    8388608
#define HB1_OFF    16777216
#define WT2_OFF    25165824     // 20,971,520 halves
#define Z16_OFF    46137344     // 20,971,520 halves (chunk: 4096 rows x 5 x 1024 f16)
#define A_OFF      67108864     // 8,388,608 halves = 4096x1024 f32 (prefix prod of f)
#define BC_OFF     75497472     // 8,388,608 halves (local c-scan)
#define BN_OFF     83886080     // 8,388,608 halves (local n-scan)
#define STATS_OFF  92274688     // 98,304 halves = 4096x12 f32
#define CARC_OFF   92372992     // 524,288 halves = 8x32768 f32
#define CARN_OFF   92897280     // 524,288 halves
#define STATE_OFF  93421568     // 524,288 halves = 2*L*B*H f32
#define FCP_OFF    93945856     // 131,072 halves = 65536 f32
// total ~188 MB

// ---- pack W[l][j][k][n] fp32 -> f16 B-frag layout (verified r1-r7)
__global__ __launch_bounds__(256) void pack_w(const float* __restrict__ W,
                                              _Float16* __restrict__ Wt2) {
  int tile = blockIdx.x;
  int m_idx = tile >> 8;            // 0..19  (= l*5+jj)
  int kt = (tile >> 4) & 15, ntt = tile & 15;
  int l = m_idx / 5, jj = m_idx % 5;
  const float* Wf = W + ((size_t)(l * 6 + jj + 1) << 20);
  _Float16* out = Wt2 + ((size_t)m_idx << 20);
  __shared__ float ts[64][65];
  int k0 = kt * 64, n0 = ntt * 64;
#pragma unroll
  for (int s = 0; s < 16; ++s) {
    int e = threadIdx.x + s * 256;
    int kk = e >> 6, col = e & 63;
    ts[kk][col] = Wf[(size_t)(k0 + kk) * H + n0 + col];
  }
  __syncthreads();
#pragma unroll
  for (int gi = 0; gi < 2; ++gi) {
    int g = threadIdx.x * 2 + gi;   // 0..511
    int l64 = g & 63, ksl = (g >> 6) & 1, ntl = g >> 7;
    int nn = l64 & 15, kh = l64 >> 4;
    half8 tmp;
#pragma unroll
    for (int e = 0; e < 8; ++e)
      tmp[e] = (_Float16)ts[ksl * 32 + kh * 8 + e][ntl * 16 + nn];
    *(half8*)&out[(size_t)((ntt * 4 + ntl) * 32 + kt * 2 + ksl) * 512 + (size_t)l64 * 8] = tmp;
  }
}

// ---- pack x fp32 -> f16 A-frag layout per t (verified r1-r7)
__global__ __launch_bounds__(256) void pack_x(const float* __restrict__ x,
                                              _Float16* __restrict__ x_pk) {
  int t = blockIdx.x;
  __shared__ float ld[32][257];
  for (int c = 0; c < 4; ++c) {
#pragma unroll
    for (int s = 0; s < 32; ++s) {
      int e2 = threadIdx.x + s * 256;
      int b = e2 >> 8, col = e2 & 255;
      ld[b][col] = x[((size_t)b * T + t) * H + c * 256 + col];
    }
    __syncthreads();
#pragma unroll
    for (int s3 = 0; s3 < 4; ++s3) {
      int gg = threadIdx.x * 4 + s3;  // 0..1023
      int l64 = gg & 63, ksl = (gg >> 6) & 7, bt = gg >> 9;
      int nn = l64 & 15, kh = l64 >> 4;
      int b = bt * 16 + nn;
      half8 tmp;
#pragma unroll
      for (int e = 0; e < 8; ++e)
        tmp[e] = (_Float16)ld[b][ksl * 32 + kh * 8 + e];
      *(half8*)&x_pk[(size_t)t * 32768 + (size_t)bt * 16384 +
                     (size_t)(c * 8 + ksl) * 512 + (size_t)l64 * 8] = tmp;
    }
    __syncthreads();
  }
}

// ---- GEMM: block 128m x 256n, 8 waves (2wm x 4wn), wave 64m x 64n.
// Counted-vmcnt pipeline: 2-deep register prefetch (loads for ks+2 issued
// while ds_writing ks+1 -> compiler emits vmcnt(3), not 0) and raw
// lgkmcnt(0)+s_barrier (no vmcnt drain) so prefetch loads stay in flight
// across the barrier. Buffers disjoint (write nxt, read cur) -> race-free.
__global__ __launch_bounds__(512) void gemm_big(
    const _Float16* __restrict__ A_pk, const _Float16* __restrict__ Wl,
    _Float16* __restrict__ z16, int t0) {
  int raw = blockIdx.x;
  int swz = (raw & 7) * 80 + (raw >> 3);   // 640 = 8 XCD x 80, bijective
  int bm = swz & 31;
  int bn = swz >> 5;
  int w = threadIdx.x >> 6, lane = threadIdx.x & 63;
  int wm = w >> 2, wn = w & 3;

  __shared__ _Float16 smem[24576];   // 2 x 12288; epilogue reuses as cz[64][264]

  int j = bn >> 2;
  // this wave's 3 staging frags (24 total: A f=0..7, B f=8..23)
  const _Float16* gsrc[3];
  int ldst[3];
#pragma unroll
  for (int q = 0; q < 3; ++q) {
    int f = w * 3 + q;
    if (f < 8) {
      gsrc[q] = A_pk + (size_t)(t0 * 2 + bm * 8 + f) * 16384 + lane * 8;
      ldst[q] = f * 512 + lane * 8;
    } else {
      int nf = f - 8;
      gsrc[q] = Wl + ((size_t)j << 20) + (size_t)((bn & 3) * 16 + nf) * 16384 + lane * 8;
      ldst[q] = 4096 + nf * 512 + lane * 8;
    }
  }

  // prologue: stage ks=0 into buffer 0; prefetch ks=1 into stA
  half8 stA[3], stB[3];
#pragma unroll
  for (int q = 0; q < 3; ++q) stA[q] = *(const half8*)(gsrc[q]);
#pragma unroll
  for (int q = 0; q < 3; ++q) *(half8*)&smem[ldst[q]] = stA[q];
#pragma unroll
  for (int q = 0; q < 3; ++q) stA[q] = *(const half8*)(gsrc[q] + 512);
  __syncthreads();

  f32x4 acc[4][4] = {};
  int ardo = wm * 2048 + lane * 8;          // a-frag read base (within buffer)
  int brdo = 4096 + wn * 2048 + lane * 8;   // b-frag read base

  for (int ks = 0; ks < 32; ks += 2) {
    // ---- even sub-step: read buf0, write stA(=ks+1) -> buf1, prefetch ks+2 -> stB
    {
      if (ks + 2 < 32) {
#pragma unroll
        for (int q = 0; q < 3; ++q)
          stB[q] = *(const half8*)(gsrc[q] + (size_t)(ks + 2) * 512);
      }
      half8 a[4], b[4];
#pragma unroll
      for (int i = 0; i < 4; ++i) a[i] = *(const half8*)&smem[ardo + i * 512];
#pragma unroll
      for (int i = 0; i < 4; ++i) b[i] = *(const half8*)&smem[brdo + i * 512];
#pragma unroll
      for (int i = 0; i < 4; ++i)
#pragma unroll
        for (int jf = 0; jf < 4; ++jf)
          acc[i][jf] = __builtin_amdgcn_mfma_f32_16x16x32_f16(a[i], b[jf], acc[i][jf], 0, 0, 0);
#pragma unroll
      for (int q = 0; q < 3; ++q) *(half8*)&smem[12288 + ldst[q]] = stA[q];
      asm volatile("s_waitcnt lgkmcnt(0)" ::: "memory");
      __builtin_amdgcn_s_barrier();
      __builtin_amdgcn_sched_barrier(0);
    }
    // ---- odd sub-step: read buf1, write stB(=ks+2) -> buf0, prefetch ks+3 -> stA
    {
      if (ks + 3 < 32) {
#pragma unroll
        for (int q = 0; q < 3; ++q)
          stA[q] = *(const half8*)(gsrc[q] + (size_t)(ks + 3) * 512);
      }
      half8 a[4], b[4];
#pragma unroll
      for (int i = 0; i < 4; ++i) a[i] = *(const half8*)&smem[12288 + ardo + i * 512];
#pragma unroll
      for (int i = 0; i < 4; ++i) b[i] = *(const half8*)&smem[12288 + brdo + i * 512];
#pragma unroll
      for (int i = 0; i < 4; ++i)
#pragma unroll
        for (int jf = 0; jf < 4; ++jf)
          acc[i][jf] = __builtin_amdgcn_mfma_f32_16x16x32_f16(a[i], b[jf], acc[i][jf], 0, 0, 0);
      if (ks + 2 < 32) {
#pragma unroll
        for (int q = 0; q < 3; ++q) *(half8*)&smem[ldst[q]] = stB[q];
        asm volatile("s_waitcnt lgkmcnt(0)" ::: "memory");
        __builtin_amdgcn_s_barrier();
        __builtin_amdgcn_sched_barrier(0);
      }
    }
  }
  __syncthreads();   // full drain before smem repurpose (epilogue cz overlaps buf1)

  // epilogue (verified r3-r7): stage C tile via LDS, store half8 rows
  _Float16 (*cz)[264] = (_Float16(*)[264])smem;
  int hb0 = (bn & 3) * 256;
  for (int p = 0; p < 2; ++p) {
    if (p) __syncthreads();
    if (wm == p) {
#pragma unroll
      for (int i = 0; i < 4; ++i)
#pragma unroll
        for (int jf = 0; jf < 4; ++jf)
#pragma unroll
          for (int r = 0; r < 4; ++r)
            cz[i * 16 + (lane >> 4) * 4 + r][wn * 64 + jf * 16 + (lane & 15)] =
                (_Float16)acc[i][jf][r];
    }
    __syncthreads();
#pragma unroll
    for (int s = 0; s < 4; ++s) {
      int e = threadIdx.x + s * 512;
      int r = e >> 5, h8 = e & 31;
      int m_local = bm * 128 + p * 64 + r;
      half8 vv = *(const half8*)&cz[r][h8 * 8];
      *(half8*)&z16[((size_t)m_local * 5 + j) * 1024 + hb0 + h8 * 8] = vv;
    }
  }
}

// ---- per-row LN stats + ksum (verified r3-r7)
__global__ __launch_bounds__(256) void stats_kernel(
    const _Float16* __restrict__ z16, const float* __restrict__ bias,
    const float* __restrict__ ln_g, const float* __restrict__ ln_b,
    float* __restrict__ stats, int l) {
  int row = blockIdx.x, tid = threadIdx.x;
  int h0 = tid * 4;
  float red[13];
#pragma unroll
  for (int jj = 0; jj < 5; ++jj) {
    half4 z4 = *(const half4*)&z16[((size_t)row * 5 + jj) * 1024 + h0];
    float4 bb = *(const float4*)&bias[(size_t)(l * 6 + 1 + jj) * H + h0];
    float vx = (float)z4[0] + bb.x, vy = (float)z4[1] + bb.y,
          vz = (float)z4[2] + bb.z, vw = (float)z4[3] + bb.w;
    red[jj * 2] = vx + vy + vz + vw;
    red[jj * 2 + 1] = vx * vx + vy * vy + vz * vz + vw * vw;
    if (jj == 0) {
      float4 g = *(const float4*)&ln_g[(size_t)(l * 6 + 1) * H + h0];
      float4 be = *(const float4*)&ln_b[(size_t)(l * 6 + 1) * H + h0];
      red[10] = vx * g.x + vy * g.y + vz * g.z + vw * g.w;
      red[11] = g.x + g.y + g.z + g.w;
      red[12] = be.x + be.y + be.z + be.w;
    }
  }
#pragma unroll
  for (int off = 32; off; off >>= 1)
#pragma unroll
    for (int q = 0; q < 13; ++q) red[q] += __shfl_down(red[q], off);
  __shared__ float sb[4][13];
  if ((tid & 63) == 0) {
#pragma unroll
    for (int q = 0; q < 13; ++q) sb[tid >> 6][q] = red[q];
  }
  __syncthreads();
  if (tid == 0) {
    float st[13];
#pragma unroll
    for (int q = 0; q < 13; ++q) st[q] = sb[0][q] + sb[1][q] + sb[2][q] + sb[3][q];
    float* so = stats + (size_t)row * 12;
#pragma unroll
    for (int jj = 0; jj < 5; ++jj) {
      float mu = st[jj * 2] * (1.0f / H);
      float var = st[jj * 2 + 1] * (1.0f / H) - mu * mu;
      so[jj * 2] = mu;
      so[jj * 2 + 1] = rsqrtf(var + 1e-5f);
    }
    float mu0 = st[0] * (1.0f / H);
    float rs0 = rsqrtf(st[1] * (1.0f / H) - mu0 * mu0 + 1e-5f);
    so[10] = rs0 * (st[10] - mu0 * st[11]) + st[12];
    so[11] = 0.f;
  }
}

// ---- scan pass 1: per-segment local scans, scalar per-h (r5-verified:
// 262144 threads / 1024 blocks = 16 waves/CU -- occupancy beats vec4 here)
__global__ __launch_bounds__(256) void scan_p1(
    const _Float16* __restrict__ z16, const float* __restrict__ stats,
    const float* __restrict__ bias, const float* __restrict__ ln_g,
    const float* __restrict__ ln_b, float* __restrict__ Abuf,
    float* __restrict__ Bc, float* __restrict__ Bn, int l) {
  int idx = blockIdx.x * 256 + threadIdx.x;   // 262144 threads
  int h = idx & 1023;
  int bs = idx >> 10;
  int b = bs & 31, seg = bs >> 5;

  float bz[4], gg[4], bb[4];
#pragma unroll
  for (int jj = 0; jj < 4; ++jj) {
    bz[jj] = bias[(size_t)(l * 6 + 1 + jj) * H + h];
    gg[jj] = ln_g[(size_t)(l * 6 + 1 + jj) * H + h];
    bb[jj] = ln_b[(size_t)(l * 6 + 1 + jj) * H + h];
  }
  float A = 1.f, bc = 0.f, bn = 0.f;
#pragma unroll 2
  for (int u = 0; u < SEGLEN; ++u) {
    int row = (seg * SEGLEN + u) * 32 + b;
    size_t zb = ((size_t)row * 5) * 1024 + h;
    float zk = (float)z16[zb];
    float zv = (float)z16[zb + 1024];
    float zi = (float)z16[zb + 2048];
    float zf = (float)z16[zb + 3072];
    const float* st = stats + (size_t)row * 12;
    float k   = (zk + bz[0] - st[0]) * st[1] * gg[0] + bb[0];
    float v   = (zv + bz[1] - st[2]) * st[3] * gg[1] + bb[1];
    float zi_ = (zi + bz[2] - st[4]) * st[5] * gg[2] + bb[2];
    float zf_ = (zf + bz[3] - st[6]) * st[7] * gg[3] + bb[3];
    float iv = __expf(zi_);
    float fv = 1.f / (1.f + __expf(-zf_));
    A *= fv;
    bn = fv * bn + iv * k;
    bc = fv * bc + iv * (st[10] * v);
    size_t o = (size_t)row * 1024 + h;
    Abuf[o] = A;
    Bn[o] = bn;
    Bc[o] = bc;
  }
}

// ---- scan pass 2: carry-in per segment (verified r4-r7)
__global__ __launch_bounds__(256) void scan_p2(
    const float* __restrict__ Abuf, const float* __restrict__ Bc,
    const float* __restrict__ Bn, float* __restrict__ state,
    float* __restrict__ carC, float* __restrict__ carN, int l, int t0) {
  int idx = blockIdx.x * 256 + threadIdx.x;   // 32768
  int h = idx & 1023, b = idx >> 10;
  size_t sidx = ((size_t)l * B + b) * H + h;
  float cc = 0.f, nn = 0.f;
  if (t0 > 0) {
    cc = state[sidx];
    nn = state[(size_t)L * B * H + sidx];
  }
#pragma unroll
  for (int seg = 0; seg < NSEG; ++seg) {
    size_t coff = (size_t)seg * 32768 + (size_t)b * 1024 + h;
    carC[coff] = cc;
    carN[coff] = nn;
    int rowLast = (seg * SEGLEN + SEGLEN - 1) * 32 + b;
    size_t o = (size_t)rowLast * 1024 + h;
    float a = Abuf[o];
    cc = Bc[o] + a * cc;
    nn = Bn[o] + a * nn;
  }
  state[sidx] = cc;
  state[(size_t)L * B * H + sidx] = nn;
}

// ---- final (verified r4-r7)
__global__ __launch_bounds__(256) void final_kernel(
    const _Float16* __restrict__ z16, const float* __restrict__ stats,
    const float* __restrict__ bias, const float* __restrict__ ln_g,
    const float* __restrict__ ln_b, const float* __restrict__ Abuf,
    const float* __restrict__ Bc, const float* __restrict__ Bn,
    const float* __restrict__ carC, const float* __restrict__ carN,
    const _Float16* __restrict__ hin, _Float16* __restrict__ hout,
    float* __restrict__ out, int l, int t0) {
  int row = blockIdx.x;
  int b = row & 31, tc = row >> 5, t = t0 + tc, seg = tc / SEGLEN;
  int tid = threadIdx.x, h0 = tid * 4;
  size_t o = (size_t)row * 1024 + h0;
  size_t coff = (size_t)seg * 32768 + (size_t)b * 1024 + h0;
  float4 a4 = *(const float4*)&Abuf[o];
  float4 bn4 = *(const float4*)&Bn[o];
  float4 bc4 = *(const float4*)&Bc[o];
  float4 cN = *(const float4*)&carN[coff];
  float4 cC = *(const float4*)&carC[coff];
  float nn[4] = {bn4.x + a4.x * cN.x, bn4.y + a4.y * cN.y,
                 bn4.z + a4.z * cN.z, bn4.w + a4.w * cN.w};
  float cc[4] = {bc4.x + a4.x * cC.x, bc4.y + a4.y * cC.y,
                 bc4.z + a4.z * cC.z, bc4.w + a4.w * cC.w};

  float ss = nn[0] * nn[0] + nn[1] * nn[1] + nn[2] * nn[2] + nn[3] * nn[3];
#pragma unroll
  for (int off = 32; off; off >>= 1) ss += __shfl_down(ss, off);
  __shared__ float sb[4];
  if ((tid & 63) == 0) sb[tid >> 6] = ss;
  __syncthreads();
  float rn = 1.f / (sqrtf(sb[0] + sb[1] + sb[2] + sb[3]) + 1e-8f);

  half4 zo4 = *(const half4*)&z16[((size_t)row * 5 + 4) * 1024 + h0];
  const float* st = stats + (size_t)row * 12;
  float mu = st[8], rs = st[9];
  float4 bz = *(const float4*)&bias[(size_t)(l * 6 + 5) * H + h0];
  float4 g4 = *(const float4*)&ln_g[(size_t)(l * 6 + 5) * H + h0];
  float4 be4 = *(const float4*)&ln_b[(size_t)(l * 6 + 5) * H + h0];
  float gv[4] = {g4.x, g4.y, g4.z, g4.w};
  float bev[4] = {be4.x, be4.y, be4.z, be4.w};
  float zov[4] = {(float)zo4[0] + bz.x, (float)zo4[1] + bz.y,
                  (float)zo4[2] + bz.z, (float)zo4[3] + bz.w};

  size_t hfoff = (size_t)(b >> 4) * 16384 + (size_t)(h0 >> 5) * 512 +
                 (size_t)((((h0 & 31) >> 3) * 16) + (b & 15)) * 8 + (h0 & 7);
  half4 rin;
  if (l > 0) rin = *(const half4*)&hin[(size_t)t * 32768 + hfoff];

  float hh[4];
#pragma unroll
  for (int u = 0; u < 4; ++u) {
    float ov = 1.f / (1.f + __expf(-((zov[u] - mu) * rs * gv[u] + bev[u])));
    float targ = cc[u] * (nn[u] * rn);
    float e2 = __expf(-2.f * fabsf(targ));
    float th = copysignf((1.f - e2) / (1.f + e2), targ);
    hh[u] = ov * th + ((l > 0) ? (float)rin[u] : 0.f);
  }
  half4 hx;
  hx[0] = (_Float16)hh[0]; hx[1] = (_Float16)hh[1];
  hx[2] = (_Float16)hh[2]; hx[3] = (_Float16)hh[3];
  *(half4*)&hout[(size_t)t * 32768 + hfoff] = hx;

  if (t == T - 1) {
    *(float4*)&out[8192 + (size_t)l * 32768 + (size_t)b * 1024 + h0] =
        make_float4(hh[0], hh[1], hh[2], hh[3]);
    *(float4*)&out[8192 + 131072 + ((size_t)(l * B) + b) * 1024 + h0] =
        make_float4(cc[0], cc[1], cc[2], cc[3]);
    *(float4*)&out[8192 + 262144 + ((size_t)(l * B) + b) * 1024 + h0] =
        make_float4(nn[0], nn[1], nn[2], nn[3]);
  }
}

// ---- fc: split-K partials + reduce (verified r4-r7)
__global__ __launch_bounds__(256) void fc_part(
    const float* __restrict__ out_h, const float* __restrict__ fc_w,
    float* __restrict__ partial) {
  int b = blockIdx.x >> 3, kh = blockIdx.x & 7;
  int o = threadIdx.x;
  const float* hr = out_h + (size_t)b * 1024 + kh * 128;
  const float* wp = fc_w + (size_t)kh * 128 * O + o;
  float acc = 0.f;
#pragma unroll 8
  for (int h = 0; h < 128; ++h)
    acc = fmaf(hr[h], wp[(size_t)h * O], acc);
  partial[((size_t)kh * 32 + b) * O + o] = acc;
}

__global__ __launch_bounds__(256) void fc_reduce(
    const float* __restrict__ partial, const float* __restrict__ fc_b,
    float* __restrict__ out) {
  int b = blockIdx.x, o = threadIdx.x;
  float acc = fc_b[o];
#pragma unroll
  for (int kh = 0; kh < 8; ++kh)
    acc += partial[((size_t)kh * 32 + b) * O + o];
  out[(size_t)b * O + o] = acc;
}

extern "C" void kernel_launch(void* const* d_in, const int* in_sizes, int n_in,
                              void* d_out, int out_size, void* d_ws, size_t ws_size,
                              hipStream_t stream) {
  const float* x    = (const float*)d_in[0];
  const float* W    = (const float*)d_in[1];
  const float* bias = (const float*)d_in[2];
  const float* ln_g = (const float*)d_in[3];
  const float* ln_b = (const float*)d_in[4];
  const float* fc_w = (const float*)d_in[5];
  const float* fc_b = (const float*)d_in[6];
  float* out = (float*)d_out;
  _Float16* wsh = (_Float16*)d_ws;

  _Float16* x_pk = wsh + X_PK_OFF;
  _Float16* hb[2] = {wsh + HB0_OFF, wsh + HB1_OFF};
  _Float16* Wt2  = wsh + WT2_OFF;
  _Float16* z16  = wsh + Z16_OFF;
  float* Abuf  = (float*)(wsh + A_OFF);
  float* Bc    = (float*)(wsh + BC_OFF);
  float* Bn    = (float*)(wsh + BN_OFF);
  float* stats = (float*)(wsh + STATS_OFF);
  float* carC  = (float*)(wsh + CARC_OFF);
  float* carN  = (float*)(wsh + CARN_OFF);
  float* state = (float*)(wsh + STATE_OFF);
  float* fcp   = (float*)(wsh + FCP_OFF);

  pack_w<<<5120, 256, 0, stream>>>(W, Wt2);
  pack_x<<<256, 256, 0, stream>>>(x, x_pk);

  for (int l = 0; l < L; ++l) {
    const _Float16* A_in = (l == 0) ? x_pk : hb[(l - 1) & 1];
    _Float16* h_out = hb[l & 1];
    const _Float16* Wl = Wt2 + ((size_t)(l * 5) << 20);
    for (int c = 0; c < NCHUNK; ++c) {
      int t0 = c * TCH;
      gemm_big<<<640, 512, 0, stream>>>(A_in, Wl, z16, t0);
      stats_kernel<<<4096, 256, 0, stream>>>(z16, bias, ln_g, ln_b, stats, l);
      scan_p1<<<1024, 256, 0, stream>>>(z16, stats, bias, ln_g, ln_b,
                                        Abuf, Bc, Bn, l);
      scan_p2<<<128, 256, 0, stream>>>(Abuf, Bc, Bn, state, carC, carN, l, t0);
      final_kernel<<<4096, 256, 0, stream>>>(z16, stats, bias, ln_g, ln_b,
                                             Abuf, Bc, Bn, carC, carN,
                                             A_in, h_out, out, l, t0);
    }
  }
  fc_part<<<256, 256, 0, stream>>>(out + 8192 + 3 * 32768, fc_w, fcp);
  fc_reduce<<<B, 256, 0, stream>>>(fcp, fc_b, out);
}

// Round 10
// 793.555 us; speedup vs baseline: 1.3541x; 1.1264x over previous
//
#include <hip/hip_runtime.h>
#include <hip/hip_bf16.h>
#include <math.h>

#define H 1024
#define B 32
#define T 256
#define L 4
#define O 256
#define SEGLEN 16
#define NSEG (T / SEGLEN)   // 16

typedef _Float16 half8 __attribute__((ext_vector_type(8)));
typedef _Float16 half4 __attribute__((ext_vector_type(4)));
typedef float f32x4 __attribute__((ext_vector_type(4)));

// ws layout (offsets in halves), full-T single pass:
#define X_PK_OFF   0             // 8,388,608  (T*32 frag-rows, A-frag f16)
#define HB0_OFF    8388608       // 8,388,608
#define HB1_OFF    16777216      // 8,388,608
#define WT2_OFF    25165824      // 20,971,520 (L*5 matrices, B-frag f16)
#define Z16_OFF    46137344      // 41,943,040 (8192 rows x 5 x 1024 f16)
#define A_OFF      88080384      // 16,777,216 halves = 8192x1024 f32
#define BC_OFF     104857600     // 16,777,216
#define BN_OFF     121634816     // 16,777,216
#define STATS_OFF  138412032     // 196,608 halves = 8192x12 f32
#define CARC_OFF   138608640     // 1,048,576 halves = 16x32768 f32
#define CARN_OFF   139657216     // 1,048,576
#define STATE_OFF  140705792     // 524,288 halves = 2*L*B*H f32
#define FCP_OFF    141230080     // 131,072 halves = 65536 f32
// total ~283 MB (ws is ~400 MB per harness fill)

// ---- pack W[l][j][k][n] fp32 -> f16 B-frag layout (verified r1-r8)
__global__ __launch_bounds__(256) void pack_w(const float* __restrict__ W,
                                              _Float16* __restrict__ Wt2) {
  int tile = blockIdx.x;
  int m_idx = tile >> 8;            // 0..19  (= l*5+jj)
  int kt = (tile >> 4) & 15, ntt = tile & 15;
  int l = m_idx / 5, jj = m_idx % 5;
  const float* Wf = W + ((size_t)(l * 6 + jj + 1) << 20);
  _Float16* out = Wt2 + ((size_t)m_idx << 20);
  __shared__ float ts[64][65];
  int k0 = kt * 64, n0 = ntt * 64;
#pragma unroll
  for (int s = 0; s < 16; ++s) {
    int e = threadIdx.x + s * 256;
    int kk = e >> 6, col = e & 63;
    ts[kk][col] = Wf[(size_t)(k0 + kk) * H + n0 + col];
  }
  __syncthreads();
#pragma unroll
  for (int gi = 0; gi < 2; ++gi) {
    int g = threadIdx.x * 2 + gi;   // 0..511
    int l64 = g & 63, ksl = (g >> 6) & 1, ntl = g >> 7;
    int nn = l64 & 15, kh = l64 >> 4;
    half8 tmp;
#pragma unroll
    for (int e = 0; e < 8; ++e)
      tmp[e] = (_Float16)ts[ksl * 32 + kh * 8 + e][ntl * 16 + nn];
    *(half8*)&out[(size_t)((ntt * 4 + ntl) * 32 + kt * 2 + ksl) * 512 + (size_t)l64 * 8] = tmp;
  }
}

// ---- pack x fp32 -> f16 A-frag layout per t (verified r1-r8)
__global__ __launch_bounds__(256) void pack_x(const float* __restrict__ x,
                                              _Float16* __restrict__ x_pk) {
  int t = blockIdx.x;
  __shared__ float ld[32][257];
  for (int c = 0; c < 4; ++c) {
#pragma unroll
    for (int s = 0; s < 32; ++s) {
      int e2 = threadIdx.x + s * 256;
      int b = e2 >> 8, col = e2 & 255;
      ld[b][col] = x[((size_t)b * T + t) * H + c * 256 + col];
    }
    __syncthreads();
#pragma unroll
    for (int s3 = 0; s3 < 4; ++s3) {
      int gg = threadIdx.x * 4 + s3;  // 0..1023
      int l64 = gg & 63, ksl = (gg >> 6) & 7, bt = gg >> 9;
      int nn = l64 & 15, kh = l64 >> 4;
      int b = bt * 16 + nn;
      half8 tmp;
#pragma unroll
      for (int e = 0; e < 8; ++e)
        tmp[e] = (_Float16)ld[b][ksl * 32 + kh * 8 + e];
      *(half8*)&x_pk[(size_t)t * 32768 + (size_t)bt * 16384 +
                     (size_t)(c * 8 + ksl) * 512 + (size_t)l64 * 8] = tmp;
    }
    __syncthreads();
  }
}

// ---- GEMM full-T: M=8192, N=5120. block 128m x 256n, 8 waves, wave 64x64.
// grid 1280 = 8 XCD x (16bm x 10bn) tiles, bm-fastest inside an XCD so each
// B n-slice (0.5 MB) is reused 16x from L2. Counted-vmcnt pipeline (r8).
__global__ __launch_bounds__(512) void gemm_big(
    const _Float16* __restrict__ A_pk, const _Float16* __restrict__ Wl,
    _Float16* __restrict__ z16) {
  int raw = blockIdx.x;
  int xcd = raw & 7, c = raw >> 3;          // c in [0,160)
  int bm = (xcd >> 1) * 16 + (c & 15);      // [0,64)
  int bn = (xcd & 1) * 10 + (c >> 4);       // [0,20)
  int w = threadIdx.x >> 6, lane = threadIdx.x & 63;
  int wm = w >> 2, wn = w & 3;

  __shared__ _Float16 smem[24576];   // 2 x 12288; epilogue reuses as cz[64][264]

  int j = bn >> 2;
  const _Float16* gsrc[3];
  int ldst[3];
#pragma unroll
  for (int q = 0; q < 3; ++q) {
    int f = w * 3 + q;
    if (f < 8) {
      gsrc[q] = A_pk + (size_t)(bm * 8 + f) * 16384 + lane * 8;
      ldst[q] = f * 512 + lane * 8;
    } else {
      int nf = f - 8;
      gsrc[q] = Wl + ((size_t)j << 20) + (size_t)((bn & 3) * 16 + nf) * 16384 + lane * 8;
      ldst[q] = 4096 + nf * 512 + lane * 8;
    }
  }

  // prologue: stage ks=0 into buffer 0; prefetch ks=1 into stA
  half8 stA[3], stB[3];
#pragma unroll
  for (int q = 0; q < 3; ++q) stA[q] = *(const half8*)(gsrc[q]);
#pragma unroll
  for (int q = 0; q < 3; ++q) *(half8*)&smem[ldst[q]] = stA[q];
#pragma unroll
  for (int q = 0; q < 3; ++q) stA[q] = *(const half8*)(gsrc[q] + 512);
  __syncthreads();

  f32x4 acc[4][4] = {};
  int ardo = wm * 2048 + lane * 8;
  int brdo = 4096 + wn * 2048 + lane * 8;

  for (int ks = 0; ks < 32; ks += 2) {
    // even: read buf0, write stA(ks+1)->buf1, prefetch ks+2->stB
    {
      if (ks + 2 < 32) {
#pragma unroll
        for (int q = 0; q < 3; ++q)
          stB[q] = *(const half8*)(gsrc[q] + (size_t)(ks + 2) * 512);
      }
      half8 a[4], b[4];
#pragma unroll
      for (int i = 0; i < 4; ++i) a[i] = *(const half8*)&smem[ardo + i * 512];
#pragma unroll
      for (int i = 0; i < 4; ++i) b[i] = *(const half8*)&smem[brdo + i * 512];
#pragma unroll
      for (int i = 0; i < 4; ++i)
#pragma unroll
        for (int jf = 0; jf < 4; ++jf)
          acc[i][jf] = __builtin_amdgcn_mfma_f32_16x16x32_f16(a[i], b[jf], acc[i][jf], 0, 0, 0);
#pragma unroll
      for (int q = 0; q < 3; ++q) *(half8*)&smem[12288 + ldst[q]] = stA[q];
      asm volatile("s_waitcnt lgkmcnt(0)" ::: "memory");
      __builtin_amdgcn_s_barrier();
      __builtin_amdgcn_sched_barrier(0);
    }
    // odd: read buf1, write stB(ks+2)->buf0, prefetch ks+3->stA
    {
      if (ks + 3 < 32) {
#pragma unroll
        for (int q = 0; q < 3; ++q)
          stA[q] = *(const half8*)(gsrc[q] + (size_t)(ks + 3) * 512);
      }
      half8 a[4], b[4];
#pragma unroll
      for (int i = 0; i < 4; ++i) a[i] = *(const half8*)&smem[12288 + ardo + i * 512];
#pragma unroll
      for (int i = 0; i < 4; ++i) b[i] = *(const half8*)&smem[12288 + brdo + i * 512];
#pragma unroll
      for (int i = 0; i < 4; ++i)
#pragma unroll
        for (int jf = 0; jf < 4; ++jf)
          acc[i][jf] = __builtin_amdgcn_mfma_f32_16x16x32_f16(a[i], b[jf], acc[i][jf], 0, 0, 0);
      if (ks + 2 < 32) {
#pragma unroll
        for (int q = 0; q < 3; ++q) *(half8*)&smem[ldst[q]] = stB[q];
        asm volatile("s_waitcnt lgkmcnt(0)" ::: "memory");
        __builtin_amdgcn_s_barrier();
        __builtin_amdgcn_sched_barrier(0);
      }
    }
  }
  __syncthreads();

  // epilogue (verified r3-r8)
  _Float16 (*cz)[264] = (_Float16(*)[264])smem;
  int hb0 = (bn & 3) * 256;
  for (int p = 0; p < 2; ++p) {
    if (p) __syncthreads();
    if (wm == p) {
#pragma unroll
      for (int i = 0; i < 4; ++i)
#pragma unroll
        for (int jf = 0; jf < 4; ++jf)
#pragma unroll
          for (int r = 0; r < 4; ++r)
            cz[i * 16 + (lane >> 4) * 4 + r][wn * 64 + jf * 16 + (lane & 15)] =
                (_Float16)acc[i][jf][r];
    }
    __syncthreads();
#pragma unroll
    for (int s = 0; s < 4; ++s) {
      int e = threadIdx.x + s * 512;
      int r = e >> 5, h8 = e & 31;
      int m_local = bm * 128 + p * 64 + r;
      half8 vv = *(const half8*)&cz[r][h8 * 8];
      *(half8*)&z16[((size_t)m_local * 5 + j) * 1024 + hb0 + h8 * 8] = vv;
    }
  }
}

// ---- per-row LN stats + ksum (verified r3-r8); grid 8192
__global__ __launch_bounds__(256) void stats_kernel(
    const _Float16* __restrict__ z16, const float* __restrict__ bias,
    const float* __restrict__ ln_g, const float* __restrict__ ln_b,
    float* __restrict__ stats, int l) {
  int row = blockIdx.x, tid = threadIdx.x;
  int h0 = tid * 4;
  float red[13];
#pragma unroll
  for (int jj = 0; jj < 5; ++jj) {
    half4 z4 = *(const half4*)&z16[((size_t)row * 5 + jj) * 1024 + h0];
    float4 bb = *(const float4*)&bias[(size_t)(l * 6 + 1 + jj) * H + h0];
    float vx = (float)z4[0] + bb.x, vy = (float)z4[1] + bb.y,
          vz = (float)z4[2] + bb.z, vw = (float)z4[3] + bb.w;
    red[jj * 2] = vx + vy + vz + vw;
    red[jj * 2 + 1] = vx * vx + vy * vy + vz * vz + vw * vw;
    if (jj == 0) {
      float4 g = *(const float4*)&ln_g[(size_t)(l * 6 + 1) * H + h0];
      float4 be = *(const float4*)&ln_b[(size_t)(l * 6 + 1) * H + h0];
      red[10] = vx * g.x + vy * g.y + vz * g.z + vw * g.w;
      red[11] = g.x + g.y + g.z + g.w;
      red[12] = be.x + be.y + be.z + be.w;
    }
  }
#pragma unroll
  for (int off = 32; off; off >>= 1)
#pragma unroll
    for (int q = 0; q < 13; ++q) red[q] += __shfl_down(red[q], off);
  __shared__ float sb[4][13];
  if ((tid & 63) == 0) {
#pragma unroll
    for (int q = 0; q < 13; ++q) sb[tid >> 6][q] = red[q];
  }
  __syncthreads();
  if (tid == 0) {
    float st[13];
#pragma unroll
    for (int q = 0; q < 13; ++q) st[q] = sb[0][q] + sb[1][q] + sb[2][q] + sb[3][q];
    float* so = stats + (size_t)row * 12;
#pragma unroll
    for (int jj = 0; jj < 5; ++jj) {
      float mu = st[jj * 2] * (1.0f / H);
      float var = st[jj * 2 + 1] * (1.0f / H) - mu * mu;
      so[jj * 2] = mu;
      so[jj * 2 + 1] = rsqrtf(var + 1e-5f);
    }
    float mu0 = st[0] * (1.0f / H);
    float rs0 = rsqrtf(st[1] * (1.0f / H) - mu0 * mu0 + 1e-5f);
    so[10] = rs0 * (st[10] - mu0 * st[11]) + st[12];
    so[11] = 0.f;
  }
}

// ---- scan pass 1: per-segment local scans (r5/r8-verified structure);
// 524288 threads / 2048 blocks
__global__ __launch_bounds__(256) void scan_p1(
    const _Float16* __restrict__ z16, const float* __restrict__ stats,
    const float* __restrict__ bias, const float* __restrict__ ln_g,
    const float* __restrict__ ln_b, float* __restrict__ Abuf,
    float* __restrict__ Bc, float* __restrict__ Bn, int l) {
  int idx = blockIdx.x * 256 + threadIdx.x;
  int h = idx & 1023;
  int bs = idx >> 10;
  int b = bs & 31, seg = bs >> 5;   // seg in [0,16)

  float bz[4], gg[4], bb[4];
#pragma unroll
  for (int jj = 0; jj < 4; ++jj) {
    bz[jj] = bias[(size_t)(l * 6 + 1 + jj) * H + h];
    gg[jj] = ln_g[(size_t)(l * 6 + 1 + jj) * H + h];
    bb[jj] = ln_b[(size_t)(l * 6 + 1 + jj) * H + h];
  }
  float A = 1.f, bc = 0.f, bn = 0.f;
#pragma unroll 2
  for (int u = 0; u < SEGLEN; ++u) {
    int row = (seg * SEGLEN + u) * 32 + b;
    size_t zb = ((size_t)row * 5) * 1024 + h;
    float zk = (float)z16[zb];
    float zv = (float)z16[zb + 1024];
    float zi = (float)z16[zb + 2048];
    float zf = (float)z16[zb + 3072];
    const float* st = stats + (size_t)row * 12;
    float k   = (zk + bz[0] - st[0]) * st[1] * gg[0] + bb[0];
    float v   = (zv + bz[1] - st[2]) * st[3] * gg[1] + bb[1];
    float zi_ = (zi + bz[2] - st[4]) * st[5] * gg[2] + bb[2];
    float zf_ = (zf + bz[3] - st[6]) * st[7] * gg[3] + bb[3];
    float iv = __expf(zi_);
    float fv = 1.f / (1.f + __expf(-zf_));
    A *= fv;
    bn = fv * bn + iv * k;
    bc = fv * bc + iv * (st[10] * v);
    size_t o = (size_t)row * 1024 + h;
    Abuf[o] = A;
    Bn[o] = bn;
    Bc[o] = bc;
  }
}

// ---- scan pass 2: carry-in per segment (16 segs, full T)
__global__ __launch_bounds__(256) void scan_p2(
    const float* __restrict__ Abuf, const float* __restrict__ Bc,
    const float* __restrict__ Bn, float* __restrict__ carC,
    float* __restrict__ carN) {
  int idx = blockIdx.x * 256 + threadIdx.x;   // 32768
  int h = idx & 1023, b = idx >> 10;
  float cc = 0.f, nn = 0.f;
#pragma unroll
  for (int seg = 0; seg < NSEG; ++seg) {
    size_t coff = (size_t)seg * 32768 + (size_t)b * 1024 + h;
    carC[coff] = cc;
    carN[coff] = nn;
    int rowLast = (seg * SEGLEN + SEGLEN - 1) * 32 + b;
    size_t o = (size_t)rowLast * 1024 + h;
    float a = Abuf[o];
    cc = Bc[o] + a * cc;
    nn = Bn[o] + a * nn;
  }
}

// ---- final (verified r4-r8); grid 8192
__global__ __launch_bounds__(256) void final_kernel(
    const _Float16* __restrict__ z16, const float* __restrict__ stats,
    const float* __restrict__ bias, const float* __restrict__ ln_g,
    const float* __restrict__ ln_b, const float* __restrict__ Abuf,
    const float* __restrict__ Bc, const float* __restrict__ Bn,
    const float* __restrict__ carC, const float* __restrict__ carN,
    const _Float16* __restrict__ hin, _Float16* __restrict__ hout,
    float* __restrict__ out, int l) {
  int row = blockIdx.x;
  int b = row & 31, t = row >> 5, seg = t / SEGLEN;
  int tid = threadIdx.x, h0 = tid * 4;
  size_t o = (size_t)row * 1024 + h0;
  size_t coff = (size_t)seg * 32768 + (size_t)b * 1024 + h0;
  float4 a4 = *(const float4*)&Abuf[o];
  float4 bn4 = *(const float4*)&Bn[o];
  float4 bc4 = *(const float4*)&Bc[o];
  float4 cN = *(const float4*)&carN[coff];
  float4 cC = *(const float4*)&carC[coff];
  float nn[4] = {bn4.x + a4.x * cN.x, bn4.y + a4.y * cN.y,
                 bn4.z + a4.z * cN.z, bn4.w + a4.w * cN.w};
  float cc[4] = {bc4.x + a4.x * cC.x, bc4.y + a4.y * cC.y,
                 bc4.z + a4.z * cC.z, bc4.w + a4.w * cC.w};

  float ss = nn[0] * nn[0] + nn[1] * nn[1] + nn[2] * nn[2] + nn[3] * nn[3];
#pragma unroll
  for (int off = 32; off; off >>= 1) ss += __shfl_down(ss, off);
  __shared__ float sb[4];
  if ((tid & 63) == 0) sb[tid >> 6] = ss;
  __syncthreads();
  float rn = 1.f / (sqrtf(sb[0] + sb[1] + sb[2] + sb[3]) + 1e-8f);

  half4 zo4 = *(const half4*)&z16[((size_t)row * 5 + 4) * 1024 + h0];
  const float* st = stats + (size_t)row * 12;
  float mu = st[8], rs = st[9];
  float4 bz = *(const float4*)&bias[(size_t)(l * 6 + 5) * H + h0];
  float4 g4 = *(const float4*)&ln_g[(size_t)(l * 6 + 5) * H + h0];
  float4 be4 = *(const float4*)&ln_b[(size_t)(l * 6 + 5) * H + h0];
  float gv[4] = {g4.x, g4.y, g4.z, g4.w};
  float bev[4] = {be4.x, be4.y, be4.z, be4.w};
  float zov[4] = {(float)zo4[0] + bz.x, (float)zo4[1] + bz.y,
                  (float)zo4[2] + bz.z, (float)zo4[3] + bz.w};

  size_t hfoff = (size_t)(b >> 4) * 16384 + (size_t)(h0 >> 5) * 512 +
                 (size_t)((((h0 & 31) >> 3) * 16) + (b & 15)) * 8 + (h0 & 7);
  half4 rin;
  if (l > 0) rin = *(const half4*)&hin[(size_t)t * 32768 + hfoff];

  float hh[4];
#pragma unroll
  for (int u = 0; u < 4; ++u) {
    float ov = 1.f / (1.f + __expf(-((zov[u] - mu) * rs * gv[u] + bev[u])));
    float targ = cc[u] * (nn[u] * rn);
    float e2 = __expf(-2.f * fabsf(targ));
    float th = copysignf((1.f - e2) / (1.f + e2), targ);
    hh[u] = ov * th + ((l > 0) ? (float)rin[u] : 0.f);
  }
  half4 hx;
  hx[0] = (_Float16)hh[0]; hx[1] = (_Float16)hh[1];
  hx[2] = (_Float16)hh[2]; hx[3] = (_Float16)hh[3];
  *(half4*)&hout[(size_t)t * 32768 + hfoff] = hx;

  if (t == T - 1) {
    *(float4*)&out[8192 + (size_t)l * 32768 + (size_t)b * 1024 + h0] =
        make_float4(hh[0], hh[1], hh[2], hh[3]);
    *(float4*)&out[8192 + 131072 + ((size_t)(l * B) + b) * 1024 + h0] =
        make_float4(cc[0], cc[1], cc[2], cc[3]);
    *(float4*)&out[8192 + 262144 + ((size_t)(l * B) + b) * 1024 + h0] =
        make_float4(nn[0], nn[1], nn[2], nn[3]);
  }
}

// ---- fc: split-K partials + reduce (verified r4-r8)
__global__ __launch_bounds__(256) void fc_part(
    const float* __restrict__ out_h, const float* __restrict__ fc_w,
    float* __restrict__ partial) {
  int b = blockIdx.x >> 3, kh = blockIdx.x & 7;
  int o = threadIdx.x;
  const float* hr = out_h + (size_t)b * 1024 + kh * 128;
  const float* wp = fc_w + (size_t)kh * 128 * O + o;
  float acc = 0.f;
#pragma unroll 8
  for (int h = 0; h < 128; ++h)
    acc = fmaf(hr[h], wp[(size_t)h * O], acc);
  partial[((size_t)kh * 32 + b) * O + o] = acc;
}

__global__ __launch_bounds__(256) void fc_reduce(
    const float* __restrict__ partial, const float* __restrict__ fc_b,
    float* __restrict__ out) {
  int b = blockIdx.x, o = threadIdx.x;
  float acc = fc_b[o];
#pragma unroll
  for (int kh = 0; kh < 8; ++kh)
    acc += partial[((size_t)kh * 32 + b) * O + o];
  out[(size_t)b * O + o] = acc;
}

extern "C" void kernel_launch(void* const* d_in, const int* in_sizes, int n_in,
                              void* d_out, int out_size, void* d_ws, size_t ws_size,
                              hipStream_t stream) {
  const float* x    = (const float*)d_in[0];
  const float* W    = (const float*)d_in[1];
  const float* bias = (const float*)d_in[2];
  const float* ln_g = (const float*)d_in[3];
  const float* ln_b = (const float*)d_in[4];
  const float* fc_w = (const float*)d_in[5];
  const float* fc_b = (const float*)d_in[6];
  float* out = (float*)d_out;
  _Float16* wsh = (_Float16*)d_ws;

  _Float16* x_pk = wsh + X_PK_OFF;
  _Float16* hb[2] = {wsh + HB0_OFF, wsh + HB1_OFF};
  _Float16* Wt2  = wsh + WT2_OFF;
  _Float16* z16  = wsh + Z16_OFF;
  float* Abuf  = (float*)(wsh + A_OFF);
  float* Bc    = (float*)(wsh + BC_OFF);
  float* Bn    = (float*)(wsh + BN_OFF);
  float* stats = (float*)(wsh + STATS_OFF);
  float* carC  = (float*)(wsh + CARC_OFF);
  float* carN  = (float*)(wsh + CARN_OFF);
  float* fcp   = (float*)(wsh + FCP_OFF);

  pack_w<<<5120, 256, 0, stream>>>(W, Wt2);
  pack_x<<<256, 256, 0, stream>>>(x, x_pk);

  for (int l = 0; l < L; ++l) {
    const _Float16* A_in = (l == 0) ? x_pk : hb[(l - 1) & 1];
    _Float16* h_out = hb[l & 1];
    const _Float16* Wl = Wt2 + ((size_t)(l * 5) << 20);
    gemm_big<<<1280, 512, 0, stream>>>(A_in, Wl, z16);
    stats_kernel<<<8192, 256, 0, stream>>>(z16, bias, ln_g, ln_b, stats, l);
    scan_p1<<<2048, 256, 0, stream>>>(z16, stats, bias, ln_g, ln_b,
                                      Abuf, Bc, Bn, l);
    scan_p2<<<128, 256, 0, stream>>>(Abuf, Bc, Bn, carC, carN);
    final_kernel<<<8192, 256, 0, stream>>>(z16, stats, bias, ln_g, ln_b,
                                           Abuf, Bc, Bn, carC, carN,
                                           A_in, h_out, out, l);
  }
  fc_part<<<256, 256, 0, stream>>>(out + 8192 + 3 * 32768, fc_w, fcp);
  fc_reduce<<<B, 256, 0, stream>>>(fcp, fc_b, out);
}

// Round 11
// 753.712 us; speedup vs baseline: 1.4257x; 1.0529x over previous
//
#include <hip/hip_runtime.h>
#include <hip/hip_bf16.h>
#include <math.h>

#define H 1024
#define B 32
#define T 256
#define L 4
#define O 256
#define SEGLEN 16
#define NSEG (T / SEGLEN)   // 16

typedef _Float16 half8 __attribute__((ext_vector_type(8)));
typedef _Float16 half4 __attribute__((ext_vector_type(4)));
typedef float f32x4 __attribute__((ext_vector_type(4)));

// ws layout (offsets in halves), full-T single pass:
#define X_PK_OFF   0             // 8,388,608  (T*32 frag-rows, A-frag f16)
#define HB0_OFF    8388608       // 8,388,608
#define HB1_OFF    16777216      // 8,388,608
#define WT2_OFF    25165824      // 20,971,520 (L*5 matrices, B-frag f16)
#define Z16_OFF    46137344      // 41,943,040 (8192 rows x 5 x 1024 f16)
#define SEGA_OFF   88080384      // 1,048,576 halves = 16x32x1024 f32
#define SEGBC_OFF  89128960      // 1,048,576
#define SEGBN_OFF  90177536      // 1,048,576
#define STATS_OFF  91226112      // 196,608 halves = 8192x12 f32
#define CARC_OFF   91422720      // 1,048,576 halves = 16x32768 f32
#define CARN_OFF   92471296      // 1,048,576
#define FCP_OFF    93519872      // 131,072 halves = 65536 f32
// total ~188 MB

// ---- pack W[l][j][k][n] fp32 -> f16 B-frag layout (verified r1-r9)
__global__ __launch_bounds__(256) void pack_w(const float* __restrict__ W,
                                              _Float16* __restrict__ Wt2) {
  int tile = blockIdx.x;
  int m_idx = tile >> 8;            // 0..19  (= l*5+jj)
  int kt = (tile >> 4) & 15, ntt = tile & 15;
  int l = m_idx / 5, jj = m_idx % 5;
  const float* Wf = W + ((size_t)(l * 6 + jj + 1) << 20);
  _Float16* out = Wt2 + ((size_t)m_idx << 20);
  __shared__ float ts[64][65];
  int k0 = kt * 64, n0 = ntt * 64;
#pragma unroll
  for (int s = 0; s < 16; ++s) {
    int e = threadIdx.x + s * 256;
    int kk = e >> 6, col = e & 63;
    ts[kk][col] = Wf[(size_t)(k0 + kk) * H + n0 + col];
  }
  __syncthreads();
#pragma unroll
  for (int gi = 0; gi < 2; ++gi) {
    int g = threadIdx.x * 2 + gi;   // 0..511
    int l64 = g & 63, ksl = (g >> 6) & 1, ntl = g >> 7;
    int nn = l64 & 15, kh = l64 >> 4;
    half8 tmp;
#pragma unroll
    for (int e = 0; e < 8; ++e)
      tmp[e] = (_Float16)ts[ksl * 32 + kh * 8 + e][ntl * 16 + nn];
    *(half8*)&out[(size_t)((ntt * 4 + ntl) * 32 + kt * 2 + ksl) * 512 + (size_t)l64 * 8] = tmp;
  }
}

// ---- pack x fp32 -> f16 A-frag layout per t (verified r1-r9)
__global__ __launch_bounds__(256) void pack_x(const float* __restrict__ x,
                                              _Float16* __restrict__ x_pk) {
  int t = blockIdx.x;
  __shared__ float ld[32][257];
  for (int c = 0; c < 4; ++c) {
#pragma unroll
    for (int s = 0; s < 32; ++s) {
      int e2 = threadIdx.x + s * 256;
      int b = e2 >> 8, col = e2 & 255;
      ld[b][col] = x[((size_t)b * T + t) * H + c * 256 + col];
    }
    __syncthreads();
#pragma unroll
    for (int s3 = 0; s3 < 4; ++s3) {
      int gg = threadIdx.x * 4 + s3;  // 0..1023
      int l64 = gg & 63, ksl = (gg >> 6) & 7, bt = gg >> 9;
      int nn = l64 & 15, kh = l64 >> 4;
      int b = bt * 16 + nn;
      half8 tmp;
#pragma unroll
      for (int e = 0; e < 8; ++e)
        tmp[e] = (_Float16)ld[b][ksl * 32 + kh * 8 + e];
      *(half8*)&x_pk[(size_t)t * 32768 + (size_t)bt * 16384 +
                     (size_t)(c * 8 + ksl) * 512 + (size_t)l64 * 8] = tmp;
    }
    __syncthreads();
  }
}

// ---- GEMM full-T (verified r9): grid 1280 = 8 XCD x (16bm x 10bn),
// counted-vmcnt 2-deep pipeline
__global__ __launch_bounds__(512) void gemm_big(
    const _Float16* __restrict__ A_pk, const _Float16* __restrict__ Wl,
    _Float16* __restrict__ z16) {
  int raw = blockIdx.x;
  int xcd = raw & 7, c = raw >> 3;          // c in [0,160)
  int bm = (xcd >> 1) * 16 + (c & 15);      // [0,64)
  int bn = (xcd & 1) * 10 + (c >> 4);       // [0,20)
  int w = threadIdx.x >> 6, lane = threadIdx.x & 63;
  int wm = w >> 2, wn = w & 3;

  __shared__ _Float16 smem[24576];   // 2 x 12288; epilogue reuses as cz[64][264]

  int j = bn >> 2;
  const _Float16* gsrc[3];
  int ldst[3];
#pragma unroll
  for (int q = 0; q < 3; ++q) {
    int f = w * 3 + q;
    if (f < 8) {
      gsrc[q] = A_pk + (size_t)(bm * 8 + f) * 16384 + lane * 8;
      ldst[q] = f * 512 + lane * 8;
    } else {
      int nf = f - 8;
      gsrc[q] = Wl + ((size_t)j << 20) + (size_t)((bn & 3) * 16 + nf) * 16384 + lane * 8;
      ldst[q] = 4096 + nf * 512 + lane * 8;
    }
  }

  half8 stA[3], stB[3];
#pragma unroll
  for (int q = 0; q < 3; ++q) stA[q] = *(const half8*)(gsrc[q]);
#pragma unroll
  for (int q = 0; q < 3; ++q) *(half8*)&smem[ldst[q]] = stA[q];
#pragma unroll
  for (int q = 0; q < 3; ++q) stA[q] = *(const half8*)(gsrc[q] + 512);
  __syncthreads();

  f32x4 acc[4][4] = {};
  int ardo = wm * 2048 + lane * 8;
  int brdo = 4096 + wn * 2048 + lane * 8;

  for (int ks = 0; ks < 32; ks += 2) {
    {
      if (ks + 2 < 32) {
#pragma unroll
        for (int q = 0; q < 3; ++q)
          stB[q] = *(const half8*)(gsrc[q] + (size_t)(ks + 2) * 512);
      }
      half8 a[4], b[4];
#pragma unroll
      for (int i = 0; i < 4; ++i) a[i] = *(const half8*)&smem[ardo + i * 512];
#pragma unroll
      for (int i = 0; i < 4; ++i) b[i] = *(const half8*)&smem[brdo + i * 512];
#pragma unroll
      for (int i = 0; i < 4; ++i)
#pragma unroll
        for (int jf = 0; jf < 4; ++jf)
          acc[i][jf] = __builtin_amdgcn_mfma_f32_16x16x32_f16(a[i], b[jf], acc[i][jf], 0, 0, 0);
#pragma unroll
      for (int q = 0; q < 3; ++q) *(half8*)&smem[12288 + ldst[q]] = stA[q];
      asm volatile("s_waitcnt lgkmcnt(0)" ::: "memory");
      __builtin_amdgcn_s_barrier();
      __builtin_amdgcn_sched_barrier(0);
    }
    {
      if (ks + 3 < 32) {
#pragma unroll
        for (int q = 0; q < 3; ++q)
          stA[q] = *(const half8*)(gsrc[q] + (size_t)(ks + 3) * 512);
      }
      half8 a[4], b[4];
#pragma unroll
      for (int i = 0; i < 4; ++i) a[i] = *(const half8*)&smem[12288 + ardo + i * 512];
#pragma unroll
      for (int i = 0; i < 4; ++i) b[i] = *(const half8*)&smem[12288 + brdo + i * 512];
#pragma unroll
      for (int i = 0; i < 4; ++i)
#pragma unroll
        for (int jf = 0; jf < 4; ++jf)
          acc[i][jf] = __builtin_amdgcn_mfma_f32_16x16x32_f16(a[i], b[jf], acc[i][jf], 0, 0, 0);
      if (ks + 2 < 32) {
#pragma unroll
        for (int q = 0; q < 3; ++q) *(half8*)&smem[ldst[q]] = stB[q];
        asm volatile("s_waitcnt lgkmcnt(0)" ::: "memory");
        __builtin_amdgcn_s_barrier();
        __builtin_amdgcn_sched_barrier(0);
      }
    }
  }
  __syncthreads();

  _Float16 (*cz)[264] = (_Float16(*)[264])smem;
  int hb0 = (bn & 3) * 256;
  for (int p = 0; p < 2; ++p) {
    if (p) __syncthreads();
    if (wm == p) {
#pragma unroll
      for (int i = 0; i < 4; ++i)
#pragma unroll
        for (int jf = 0; jf < 4; ++jf)
#pragma unroll
          for (int r = 0; r < 4; ++r)
            cz[i * 16 + (lane >> 4) * 4 + r][wn * 64 + jf * 16 + (lane & 15)] =
                (_Float16)acc[i][jf][r];
    }
    __syncthreads();
#pragma unroll
    for (int s = 0; s < 4; ++s) {
      int e = threadIdx.x + s * 512;
      int r = e >> 5, h8 = e & 31;
      int m_local = bm * 128 + p * 64 + r;
      half8 vv = *(const half8*)&cz[r][h8 * 8];
      *(half8*)&z16[((size_t)m_local * 5 + j) * 1024 + hb0 + h8 * 8] = vv;
    }
  }
}

// ---- per-row LN stats + ksum (verified r3-r9); grid 8192
__global__ __launch_bounds__(256) void stats_kernel(
    const _Float16* __restrict__ z16, const float* __restrict__ bias,
    const float* __restrict__ ln_g, const float* __restrict__ ln_b,
    float* __restrict__ stats, int l) {
  int row = blockIdx.x, tid = threadIdx.x;
  int h0 = tid * 4;
  float red[13];
#pragma unroll
  for (int jj = 0; jj < 5; ++jj) {
    half4 z4 = *(const half4*)&z16[((size_t)row * 5 + jj) * 1024 + h0];
    float4 bb = *(const float4*)&bias[(size_t)(l * 6 + 1 + jj) * H + h0];
    float vx = (float)z4[0] + bb.x, vy = (float)z4[1] + bb.y,
          vz = (float)z4[2] + bb.z, vw = (float)z4[3] + bb.w;
    red[jj * 2] = vx + vy + vz + vw;
    red[jj * 2 + 1] = vx * vx + vy * vy + vz * vz + vw * vw;
    if (jj == 0) {
      float4 g = *(const float4*)&ln_g[(size_t)(l * 6 + 1) * H + h0];
      float4 be = *(const float4*)&ln_b[(size_t)(l * 6 + 1) * H + h0];
      red[10] = vx * g.x + vy * g.y + vz * g.z + vw * g.w;
      red[11] = g.x + g.y + g.z + g.w;
      red[12] = be.x + be.y + be.z + be.w;
    }
  }
#pragma unroll
  for (int off = 32; off; off >>= 1)
#pragma unroll
    for (int q = 0; q < 13; ++q) red[q] += __shfl_down(red[q], off);
  __shared__ float sb[4][13];
  if ((tid & 63) == 0) {
#pragma unroll
    for (int q = 0; q < 13; ++q) sb[tid >> 6][q] = red[q];
  }
  __syncthreads();
  if (tid == 0) {
    float st[13];
#pragma unroll
    for (int q = 0; q < 13; ++q) st[q] = sb[0][q] + sb[1][q] + sb[2][q] + sb[3][q];
    float* so = stats + (size_t)row * 12;
#pragma unroll
    for (int jj = 0; jj < 5; ++jj) {
      float mu = st[jj * 2] * (1.0f / H);
      float var = st[jj * 2 + 1] * (1.0f / H) - mu * mu;
      so[jj * 2] = mu;
      so[jj * 2 + 1] = rsqrtf(var + 1e-5f);
    }
    float mu0 = st[0] * (1.0f / H);
    float rs0 = rsqrtf(st[1] * (1.0f / H) - mu0 * mu0 + 1e-5f);
    so[10] = rs0 * (st[10] - mu0 * st[11]) + st[12];
    so[11] = 0.f;
  }
}

// ---- scan pass 1 (aggregates only): per-(seg,b,h) local scan; writes ONLY
// the segment-final (A, bn, bc) -> 6 MB instead of 100 MB per layer.
__global__ __launch_bounds__(256) void scan_p1agg(
    const _Float16* __restrict__ z16, const float* __restrict__ stats,
    const float* __restrict__ bias, const float* __restrict__ ln_g,
    const float* __restrict__ ln_b, float* __restrict__ segA,
    float* __restrict__ segBc, float* __restrict__ segBn, int l) {
  int idx = blockIdx.x * 256 + threadIdx.x;   // 524288 threads
  int h = idx & 1023;
  int bs = idx >> 10;
  int b = bs & 31, seg = bs >> 5;   // seg in [0,16)

  float bz[4], gg[4], bb[4];
#pragma unroll
  for (int jj = 0; jj < 4; ++jj) {
    bz[jj] = bias[(size_t)(l * 6 + 1 + jj) * H + h];
    gg[jj] = ln_g[(size_t)(l * 6 + 1 + jj) * H + h];
    bb[jj] = ln_b[(size_t)(l * 6 + 1 + jj) * H + h];
  }
  float A = 1.f, bc = 0.f, bn = 0.f;
#pragma unroll 2
  for (int u = 0; u < SEGLEN; ++u) {
    int row = (seg * SEGLEN + u) * 32 + b;
    size_t zb = ((size_t)row * 5) * 1024 + h;
    float zk = (float)z16[zb];
    float zv = (float)z16[zb + 1024];
    float zi = (float)z16[zb + 2048];
    float zf = (float)z16[zb + 3072];
    const float* st = stats + (size_t)row * 12;
    float k   = (zk + bz[0] - st[0]) * st[1] * gg[0] + bb[0];
    float v   = (zv + bz[1] - st[2]) * st[3] * gg[1] + bb[1];
    float zi_ = (zi + bz[2] - st[4]) * st[5] * gg[2] + bb[2];
    float zf_ = (zf + bz[3] - st[6]) * st[7] * gg[3] + bb[3];
    float iv = __expf(zi_);
    float fv = 1.f / (1.f + __expf(-zf_));
    A *= fv;
    bn = fv * bn + iv * k;
    bc = fv * bc + iv * (st[10] * v);
  }
  size_t so = ((size_t)seg * 32 + b) * 1024 + h;
  segA[so] = A;
  segBn[so] = bn;
  segBc[so] = bc;
}

// ---- scan pass 2: carry-in per segment from aggregates
__global__ __launch_bounds__(256) void scan_p2(
    const float* __restrict__ segA, const float* __restrict__ segBc,
    const float* __restrict__ segBn, float* __restrict__ carC,
    float* __restrict__ carN) {
  int idx = blockIdx.x * 256 + threadIdx.x;   // 32768
  int h = idx & 1023, b = idx >> 10;
  float cc = 0.f, nn = 0.f;
#pragma unroll
  for (int seg = 0; seg < NSEG; ++seg) {
    size_t coff = (size_t)seg * 32768 + (size_t)b * 1024 + h;
    carC[coff] = cc;
    carN[coff] = nn;
    size_t so = ((size_t)seg * 32 + b) * 1024 + h;
    float a = segA[so];
    cc = segBc[so] + a * cc;
    nn = segBn[so] + a * nn;
  }
}

// ---- final: re-run the 16-step local recurrence with carry as init state;
// per-t block reduce of ||n||^2; compute h and outputs. block per (seg,b).
__global__ __launch_bounds__(256) void final_scan(
    const _Float16* __restrict__ z16, const float* __restrict__ stats,
    const float* __restrict__ bias, const float* __restrict__ ln_g,
    const float* __restrict__ ln_b, const float* __restrict__ carC,
    const float* __restrict__ carN, const _Float16* __restrict__ hin,
    _Float16* __restrict__ hout, float* __restrict__ out, int l) {
  int seg = blockIdx.x >> 5, b = blockIdx.x & 31;
  int tid = threadIdx.x, h0 = tid * 4;

  float bz[5][4], gg[5][4], bb[5][4];
#pragma unroll
  for (int jj = 0; jj < 5; ++jj) {
    float4 t1 = *(const float4*)&bias[(size_t)(l * 6 + 1 + jj) * H + h0];
    float4 t2 = *(const float4*)&ln_g[(size_t)(l * 6 + 1 + jj) * H + h0];
    float4 t3 = *(const float4*)&ln_b[(size_t)(l * 6 + 1 + jj) * H + h0];
    bz[jj][0] = t1.x; bz[jj][1] = t1.y; bz[jj][2] = t1.z; bz[jj][3] = t1.w;
    gg[jj][0] = t2.x; gg[jj][1] = t2.y; gg[jj][2] = t2.z; gg[jj][3] = t2.w;
    bb[jj][0] = t3.x; bb[jj][1] = t3.y; bb[jj][2] = t3.z; bb[jj][3] = t3.w;
  }

  size_t coff = (size_t)seg * 32768 + (size_t)b * 1024 + h0;
  float4 cC4 = *(const float4*)&carC[coff];
  float4 cN4 = *(const float4*)&carN[coff];
  float c_[4] = {cC4.x, cC4.y, cC4.z, cC4.w};
  float n_[4] = {cN4.x, cN4.y, cN4.z, cN4.w};

  size_t hfoff = (size_t)(b >> 4) * 16384 + (size_t)(h0 >> 5) * 512 +
                 (size_t)((((h0 & 31) >> 3) * 16) + (b & 15)) * 8 + (h0 & 7);
  __shared__ float sbuf[2][4];

  // prefetch u=0's z rows
  half4 zr[5];
  {
    int row0 = (seg * SEGLEN) * 32 + b;
#pragma unroll
    for (int jj = 0; jj < 5; ++jj)
      zr[jj] = *(const half4*)&z16[((size_t)row0 * 5 + jj) * 1024 + h0];
  }

  for (int u = 0; u < SEGLEN; ++u) {
    int t = seg * SEGLEN + u;
    int row = t * 32 + b;
    half4 zc[5];
#pragma unroll
    for (int jj = 0; jj < 5; ++jj) zc[jj] = zr[jj];
    if (u + 1 < SEGLEN) {
      int rown = (t + 1) * 32 + b;
#pragma unroll
      for (int jj = 0; jj < 5; ++jj)
        zr[jj] = *(const half4*)&z16[((size_t)rown * 5 + jj) * 1024 + h0];
    }
    half4 rin;
    if (l > 0) rin = *(const half4*)&hin[(size_t)t * 32768 + hfoff];

    const float* st = stats + (size_t)row * 12;  // block-uniform -> broadcast
    float mu0 = st[0], rs0 = st[1], mu1 = st[2], rs1 = st[3];
    float mu2 = st[4], rs2 = st[5], mu3 = st[6], rs3 = st[7];
    float mu4 = st[8], rs4 = st[9], ksum = st[10];

    float ss = 0.f;
#pragma unroll
    for (int e = 0; e < 4; ++e) {
      float k   = ((float)zc[0][e] + bz[0][e] - mu0) * rs0 * gg[0][e] + bb[0][e];
      float v   = ((float)zc[1][e] + bz[1][e] - mu1) * rs1 * gg[1][e] + bb[1][e];
      float zi_ = ((float)zc[2][e] + bz[2][e] - mu2) * rs2 * gg[2][e] + bb[2][e];
      float zf_ = ((float)zc[3][e] + bz[3][e] - mu3) * rs3 * gg[3][e] + bb[3][e];
      float iv = __expf(zi_);
      float fv = 1.f / (1.f + __expf(-zf_));
      n_[e] = fv * n_[e] + iv * k;
      c_[e] = fv * c_[e] + iv * (ksum * v);
      ss += n_[e] * n_[e];
    }
#pragma unroll
    for (int off = 32; off; off >>= 1) ss += __shfl_down(ss, off);
    if ((tid & 63) == 0) sbuf[u & 1][tid >> 6] = ss;
    __syncthreads();
    float nrm = sbuf[u & 1][0] + sbuf[u & 1][1] + sbuf[u & 1][2] + sbuf[u & 1][3];
    float rn = 1.f / (sqrtf(nrm) + 1e-8f);

    float hh[4];
#pragma unroll
    for (int e = 0; e < 4; ++e) {
      float zo_ = ((float)zc[4][e] + bz[4][e] - mu4) * rs4 * gg[4][e] + bb[4][e];
      float ov = 1.f / (1.f + __expf(-zo_));
      float targ = c_[e] * (n_[e] * rn);
      float e2 = __expf(-2.f * fabsf(targ));
      float th = copysignf((1.f - e2) / (1.f + e2), targ);
      hh[e] = ov * th + ((l > 0) ? (float)rin[e] : 0.f);
    }
    half4 hx;
    hx[0] = (_Float16)hh[0]; hx[1] = (_Float16)hh[1];
    hx[2] = (_Float16)hh[2]; hx[3] = (_Float16)hh[3];
    *(half4*)&hout[(size_t)t * 32768 + hfoff] = hx;

    if (t == T - 1) {
      *(float4*)&out[8192 + (size_t)l * 32768 + (size_t)b * 1024 + h0] =
          make_float4(hh[0], hh[1], hh[2], hh[3]);
      *(float4*)&out[8192 + 131072 + ((size_t)(l * B) + b) * 1024 + h0] =
          make_float4(c_[0], c_[1], c_[2], c_[3]);
      *(float4*)&out[8192 + 262144 + ((size_t)(l * B) + b) * 1024 + h0] =
          make_float4(n_[0], n_[1], n_[2], n_[3]);
    }
  }
}

// ---- fc: split-K partials + reduce (verified r4-r9)
__global__ __launch_bounds__(256) void fc_part(
    const float* __restrict__ out_h, const float* __restrict__ fc_w,
    float* __restrict__ partial) {
  int b = blockIdx.x >> 3, kh = blockIdx.x & 7;
  int o = threadIdx.x;
  const float* hr = out_h + (size_t)b * 1024 + kh * 128;
  const float* wp = fc_w + (size_t)kh * 128 * O + o;
  float acc = 0.f;
#pragma unroll 8
  for (int h = 0; h < 128; ++h)
    acc = fmaf(hr[h], wp[(size_t)h * O], acc);
  partial[((size_t)kh * 32 + b) * O + o] = acc;
}

__global__ __launch_bounds__(256) void fc_reduce(
    const float* __restrict__ partial, const float* __restrict__ fc_b,
    float* __restrict__ out) {
  int b = blockIdx.x, o = threadIdx.x;
  float acc = fc_b[o];
#pragma unroll
  for (int kh = 0; kh < 8; ++kh)
    acc += partial[((size_t)kh * 32 + b) * O + o];
  out[(size_t)b * O + o] = acc;
}

extern "C" void kernel_launch(void* const* d_in, const int* in_sizes, int n_in,
                              void* d_out, int out_size, void* d_ws, size_t ws_size,
                              hipStream_t stream) {
  const float* x    = (const float*)d_in[0];
  const float* W    = (const float*)d_in[1];
  const float* bias = (const float*)d_in[2];
  const float* ln_g = (const float*)d_in[3];
  const float* ln_b = (const float*)d_in[4];
  const float* fc_w = (const float*)d_in[5];
  const float* fc_b = (const float*)d_in[6];
  float* out = (float*)d_out;
  _Float16* wsh = (_Float16*)d_ws;

  _Float16* x_pk = wsh + X_PK_OFF;
  _Float16* hb[2] = {wsh + HB0_OFF, wsh + HB1_OFF};
  _Float16* Wt2  = wsh + WT2_OFF;
  _Float16* z16  = wsh + Z16_OFF;
  float* segA  = (float*)(wsh + SEGA_OFF);
  float* segBc = (float*)(wsh + SEGBC_OFF);
  float* segBn = (float*)(wsh + SEGBN_OFF);
  float* stats = (float*)(wsh + STATS_OFF);
  float* carC  = (float*)(wsh + CARC_OFF);
  float* carN  = (float*)(wsh + CARN_OFF);
  float* fcp   = (float*)(wsh + FCP_OFF);

  pack_w<<<5120, 256, 0, stream>>>(W, Wt2);
  pack_x<<<256, 256, 0, stream>>>(x, x_pk);

  for (int l = 0; l < L; ++l) {
    const _Float16* A_in = (l == 0) ? x_pk : hb[(l - 1) & 1];
    _Float16* h_out = hb[l & 1];
    const _Float16* Wl = Wt2 + ((size_t)(l * 5) << 20);
    gemm_big<<<1280, 512, 0, stream>>>(A_in, Wl, z16);
    stats_kernel<<<8192, 256, 0, stream>>>(z16, bias, ln_g, ln_b, stats, l);
    scan_p1agg<<<2048, 256, 0, stream>>>(z16, stats, bias, ln_g, ln_b,
                                         segA, segBc, segBn, l);
    scan_p2<<<128, 256, 0, stream>>>(segA, segBc, segBn, carC, carN);
    final_scan<<<512, 256, 0, stream>>>(z16, stats, bias, ln_g, ln_b,
                                        carC, carN, A_in, h_out, out, l);
  }
  fc_part<<<256, 256, 0, stream>>>(out + 8192 + 3 * 32768, fc_w, fcp);
  fc_reduce<<<B, 256, 0, stream>>>(fcp, fc_b, out);
}